// Round 2
// baseline (5678.251 us; speedup 1.0000x reference)
//
#include <hip/hip_runtime.h>
#include <cstddef>
#include <cstdint>

#define N_NODES 20000
#define N_EDGES 320000
#define NDAYS 4
#define LOOKBACK 7
#define NFEAT 5
#define HIDDEN 128
#define TOTAL_ROWS (NDAYS * N_NODES)

// ---------------- graph preprocessing ----------------

__global__ __launch_bounds__(256) void k_deg(const int* __restrict__ ei, int* __restrict__ deg) {
    int e = blockIdx.x * 256 + threadIdx.x;
    if (e < N_EDGES) atomicAdd(&deg[ei[N_EDGES + e]], 1);
}

__global__ __launch_bounds__(1024) void k_scan(const int* __restrict__ deg, int* __restrict__ row_start) {
    __shared__ int part[1024];
    int tid = threadIdx.x;
    const int chunk = (N_NODES + 1023) / 1024;  // 20
    int i0 = tid * chunk;
    int i1 = min(i0 + chunk, N_NODES);
    int s = 0;
    for (int i = i0; i < i1; ++i) s += deg[i];
    part[tid] = s;
    __syncthreads();
    for (int d = 1; d < 1024; d <<= 1) {
        int v = (tid >= d) ? part[tid - d] : 0;
        __syncthreads();
        part[tid] += v;
        __syncthreads();
    }
    int base = part[tid] - s;  // exclusive prefix
    for (int i = i0; i < i1; ++i) { row_start[i] = base; base += deg[i]; }
    if (tid == 1023) row_start[N_NODES] = part[1023];
}

__global__ __launch_bounds__(256) void k_dinv(const int* __restrict__ deg, float* __restrict__ dinv,
                                              float* __restrict__ self_norm) {
    int i = blockIdx.x * 256 + threadIdx.x;
    if (i >= N_NODES) return;
    float d = (float)(deg[i] + 1);  // +1 self loop
    dinv[i] = 1.0f / sqrtf(d);
    self_norm[i] = 1.0f / d;
}

__global__ __launch_bounds__(256) void k_fill(const int* __restrict__ ei, const int* __restrict__ row_start,
                                              int* __restrict__ cursor, const float* __restrict__ dinv,
                                              int* __restrict__ csr_src, float* __restrict__ csr_norm) {
    int e = blockIdx.x * 256 + threadIdx.x;
    if (e >= N_EDGES) return;
    int s = ei[e], d = ei[N_EDGES + e];
    int pos = row_start[d] + atomicAdd(&cursor[d], 1);
    csr_src[pos] = s;
    csr_norm[pos] = dinv[s] * dinv[d];
}

__global__ __launch_bounds__(256) void k_w2t(const float* __restrict__ W2, float* __restrict__ W2T) {
    int idx = blockIdx.x * 256 + threadIdx.x;
    if (idx >= HIDDEN * HIDDEN) return;
    int k = idx >> 7, c = idx & 127;
    W2T[c * HIDDEN + k] = W2[k * HIDDEN + c];
}

// ---------------- GCN layer 1 input GEMM: H = x_t @ W1 ----------------

__global__ __launch_bounds__(256) void k_gcn1(const float* __restrict__ x, const float* __restrict__ W1,
                                              float* __restrict__ H, int rowOffset, int nrows, int t) {
    int idx = blockIdx.x * 256 + threadIdx.x;
    int r = idx >> 6;
    if (r >= nrows) return;
    int lane = idx & 63;
    int c = lane * 2;
    const float* xp = x + (size_t)(rowOffset + r) * (LOOKBACK * NFEAT) + t * NFEAT;
    float x0 = xp[0], x1 = xp[1], x2 = xp[2], x3 = xp[3], x4 = xp[4];
    float a0 = x0 * W1[c] + x1 * W1[128 + c] + x2 * W1[256 + c] + x3 * W1[384 + c] + x4 * W1[512 + c];
    float a1 = x0 * W1[c + 1] + x1 * W1[129 + c] + x2 * W1[257 + c] + x3 * W1[385 + c] + x4 * W1[513 + c];
    float2 o; o.x = a0; o.y = a1;
    ((float2*)(H + (size_t)r * HIDDEN))[lane] = o;
}

// ---------------- GCN aggregation: Z = relu(agg + self + b) ----------------

__global__ __launch_bounds__(256) void k_agg(const float* __restrict__ H, float* __restrict__ Z,
                                             const float* __restrict__ bias,
                                             const int* __restrict__ row_start, const int* __restrict__ csr_src,
                                             const float* __restrict__ csr_norm, const float* __restrict__ self_norm,
                                             int rowOffset, int nrows) {
    int r = blockIdx.x * 4 + (threadIdx.x >> 6);
    if (r >= nrows) return;
    int lane = threadIdx.x & 63;
    int g = rowOffset + r;
    int n = g % N_NODES;
    int dayLocalBase = (g - n) - rowOffset;  // local row of this day's node 0
    const float2* H2 = (const float2*)H;
    float2 self = H2[(size_t)r * 64 + lane];
    float sn = self_norm[n];
    float acc0 = self.x * sn, acc1 = self.y * sn;
    int e1 = row_start[n + 1];
    for (int e = row_start[n]; e < e1; ++e) {
        int s = csr_src[e];
        float w = csr_norm[e];
        float2 hv = H2[(size_t)(dayLocalBase + s) * 64 + lane];
        acc0 += w * hv.x;
        acc1 += w * hv.y;
    }
    float2 b = ((const float2*)bias)[lane];
    acc0 = fmaxf(acc0 + b.x, 0.0f);
    acc1 = fmaxf(acc1 + b.y, 0.0f);
    float2 o; o.x = acc0; o.y = acc1;
    ((float2*)(Z + (size_t)r * HIDDEN))[lane] = o;
}

// ---------------- shared GEMM helpers ----------------

__device__ __forceinline__ void stage_B(float (*Bs)[129], const float* base, int tid) {
#pragma unroll
    for (int i = 0; i < 8; ++i) {
        int fid = tid + i * 256;
        int r = fid >> 5;
        int k4 = (fid & 31) * 4;
        const float4 v = *(const float4*)(base + (size_t)r * HIDDEN + k4);
        Bs[r][k4] = v.x; Bs[r][k4 + 1] = v.y; Bs[r][k4 + 2] = v.z; Bs[r][k4 + 3] = v.w;
    }
}

__device__ __forceinline__ void dot_tile(float out[4][4], const float (*Aa)[129], const float (*Bs)[129],
                                         int r0, int c0) {
#pragma unroll
    for (int i = 0; i < 4; ++i)
#pragma unroll
        for (int j = 0; j < 4; ++j) out[i][j] = 0.f;
#pragma unroll 4
    for (int k = 0; k < HIDDEN; ++k) {
        float a[4], b[4];
#pragma unroll
        for (int i = 0; i < 4; ++i) a[i] = Aa[r0 + i][k];
#pragma unroll
        for (int j = 0; j < 4; ++j) b[j] = Bs[c0 + j][k];
#pragma unroll
        for (int i = 0; i < 4; ++i)
#pragma unroll
            for (int j = 0; j < 4; ++j) out[i][j] = fmaf(a[i], b[j], out[i][j]);
    }
}

// ---------------- GCN2 GEMM: C[r][c] = sum_k A[r][k] * B[c][k]  (B = W2^T) ----------------

__global__ __launch_bounds__(256) void k_gemm2(const float* __restrict__ A, const float* __restrict__ B,
                                               float* __restrict__ C, int nrows) {
    __shared__ float As[64][129];
    __shared__ float Bs[64][129];
    int tid = threadIdx.x;
    int rblk = blockIdx.x * 64;
    int cblk = blockIdx.y * 64;
#pragma unroll
    for (int i = 0; i < 8; ++i) {
        int fid = tid + i * 256;
        int r = fid >> 5;
        int k4 = (fid & 31) * 4;
        int gr = rblk + r;
        float4 av = (gr < nrows) ? *(const float4*)(A + (size_t)gr * HIDDEN + k4)
                                 : make_float4(0.f, 0.f, 0.f, 0.f);
        As[r][k4] = av.x; As[r][k4 + 1] = av.y; As[r][k4 + 2] = av.z; As[r][k4 + 3] = av.w;
        float4 bv = *(const float4*)(B + (size_t)(cblk + r) * HIDDEN + k4);
        Bs[r][k4] = bv.x; Bs[r][k4 + 1] = bv.y; Bs[r][k4 + 2] = bv.z; Bs[r][k4 + 3] = bv.w;
    }
    __syncthreads();
    int tc = tid & 15, tr = tid >> 4;
    int r0 = tr * 4, c0 = tc * 4;
    float acc[4][4];
    dot_tile(acc, As, Bs, r0, c0);
#pragma unroll
    for (int i = 0; i < 4; ++i) {
        int gr = rblk + r0 + i;
        if (gr < nrows) {
            float4 v = make_float4(acc[i][0], acc[i][1], acc[i][2], acc[i][3]);
            *(float4*)(C + (size_t)gr * HIDDEN + cblk + c0) = v;
        }
    }
}

// ---------------- fused GRU: h' = (1-z)*n + z*h ----------------

__device__ __forceinline__ float sigm(float v) { return 1.0f / (1.0f + expf(-v)); }

__global__ __launch_bounds__(256, 1) void k_gru(const float* __restrict__ Zin, const float* __restrict__ Hin,
                                                float* __restrict__ Hout,
                                                const float* __restrict__ W_ih, const float* __restrict__ W_hh,
                                                const float* __restrict__ b_ih, const float* __restrict__ b_hh,
                                                int nrows) {
    __shared__ float Az[64][129];
    __shared__ float Ah[64][129];
    __shared__ float Bs[64][129];
    int tid = threadIdx.x;
    int rblk = blockIdx.x * 64;
    int cblk = blockIdx.y * 64;
#pragma unroll
    for (int i = 0; i < 8; ++i) {
        int fid = tid + i * 256;
        int r = fid >> 5;
        int k4 = (fid & 31) * 4;
        int gr = rblk + r;
        float4 zv, hv;
        if (gr < nrows) {
            zv = *(const float4*)(Zin + (size_t)gr * HIDDEN + k4);
            hv = *(const float4*)(Hin + (size_t)gr * HIDDEN + k4);
        } else {
            zv = make_float4(0.f, 0.f, 0.f, 0.f);
            hv = zv;
        }
        Az[r][k4] = zv.x; Az[r][k4 + 1] = zv.y; Az[r][k4 + 2] = zv.z; Az[r][k4 + 3] = zv.w;
        Ah[r][k4] = hv.x; Ah[r][k4 + 1] = hv.y; Ah[r][k4 + 2] = hv.z; Ah[r][k4 + 3] = hv.w;
    }
    int tc = tid & 15, tr = tid >> 4;
    int r0 = tr * 4, c0 = tc * 4;
    float bir[4], bhr[4], biz[4], bhz[4], bin_[4], bhn[4];
#pragma unroll
    for (int j = 0; j < 4; ++j) {
        int ch = cblk + c0 + j;
        bir[j] = b_ih[ch]; biz[j] = b_ih[128 + ch]; bin_[j] = b_ih[256 + ch];
        bhr[j] = b_hh[ch]; bhz[j] = b_hh[128 + ch]; bhn[j] = b_hh[256 + ch];
    }
    float ti[4][4], th[4][4], rg[4][4], zg[4][4], ng[4][4];

    __syncthreads();  // A tiles visible
    stage_B(Bs, W_ih + (size_t)cblk * HIDDEN, tid);
    __syncthreads();
    dot_tile(ti, Az, Bs, r0, c0);
    __syncthreads();
    stage_B(Bs, W_hh + (size_t)cblk * HIDDEN, tid);
    __syncthreads();
    dot_tile(th, Ah, Bs, r0, c0);
#pragma unroll
    for (int i = 0; i < 4; ++i)
#pragma unroll
        for (int j = 0; j < 4; ++j) rg[i][j] = sigm(ti[i][j] + bir[j] + th[i][j] + bhr[j]);

    __syncthreads();
    stage_B(Bs, W_ih + (size_t)(HIDDEN + cblk) * HIDDEN, tid);
    __syncthreads();
    dot_tile(ti, Az, Bs, r0, c0);
    __syncthreads();
    stage_B(Bs, W_hh + (size_t)(HIDDEN + cblk) * HIDDEN, tid);
    __syncthreads();
    dot_tile(th, Ah, Bs, r0, c0);
#pragma unroll
    for (int i = 0; i < 4; ++i)
#pragma unroll
        for (int j = 0; j < 4; ++j) zg[i][j] = sigm(ti[i][j] + biz[j] + th[i][j] + bhz[j]);

    __syncthreads();
    stage_B(Bs, W_ih + (size_t)(2 * HIDDEN + cblk) * HIDDEN, tid);
    __syncthreads();
    dot_tile(ti, Az, Bs, r0, c0);
    __syncthreads();
    stage_B(Bs, W_hh + (size_t)(2 * HIDDEN + cblk) * HIDDEN, tid);
    __syncthreads();
    dot_tile(th, Ah, Bs, r0, c0);
#pragma unroll
    for (int i = 0; i < 4; ++i)
#pragma unroll
        for (int j = 0; j < 4; ++j)
            ng[i][j] = tanhf(ti[i][j] + bin_[j] + rg[i][j] * (th[i][j] + bhn[j]));

#pragma unroll
    for (int i = 0; i < 4; ++i) {
        int gr = rblk + r0 + i;
        if (gr >= nrows) continue;
        float4 v;
        float* vp = &v.x;
#pragma unroll
        for (int j = 0; j < 4; ++j) {
            float hold = Ah[r0 + i][cblk + c0 + j];
            vp[j] = (1.0f - zg[i][j]) * ng[i][j] + zg[i][j] * hold;
        }
        *(float4*)(Hout + (size_t)gr * HIDDEN + cblk + c0) = v;
    }
}

// ---------------- output head: softmax(h @ W_out + b_out) ----------------

__global__ __launch_bounds__(256) void k_out(const float* __restrict__ Hc, const float* __restrict__ Wo,
                                             const float* __restrict__ bo, float* __restrict__ out,
                                             int rowOffset, int nrows) {
    int r = blockIdx.x * 4 + (threadIdx.x >> 6);
    if (r >= nrows) return;
    int lane = threadIdx.x & 63;
    float2 hv = ((const float2*)(Hc + (size_t)r * HIDDEN))[lane];
    float l[5];
#pragma unroll
    for (int j = 0; j < 5; ++j) {
        float p = hv.x * Wo[(2 * lane) * 5 + j] + hv.y * Wo[(2 * lane + 1) * 5 + j];
#pragma unroll
        for (int s = 1; s < 64; s <<= 1) p += __shfl_xor(p, s);
        l[j] = p + bo[j];
    }
    float m = fmaxf(fmaxf(fmaxf(l[0], l[1]), fmaxf(l[2], l[3])), l[4]);
    float e0 = expf(l[0] - m), e1 = expf(l[1] - m), e2 = expf(l[2] - m), e3 = expf(l[3] - m), e4 = expf(l[4] - m);
    float inv = 1.0f / (e0 + e1 + e2 + e3 + e4);
    if (lane < 5) {
        float ej = lane == 0 ? e0 : lane == 1 ? e1 : lane == 2 ? e2 : lane == 3 ? e3 : e4;
        out[(size_t)(rowOffset + r) * 5 + lane] = ej * inv;
    }
}

// ---------------- launch ----------------

extern "C" void kernel_launch(void* const* d_in, const int* in_sizes, int n_in,
                              void* d_out, int out_size, void* d_ws, size_t ws_size,
                              hipStream_t stream) {
    const float* x     = (const float*)d_in[0];
    const int*   ei    = (const int*)d_in[1];
    const float* W1    = (const float*)d_in[2];
    const float* b1    = (const float*)d_in[3];
    const float* W2    = (const float*)d_in[4];
    const float* b2    = (const float*)d_in[5];
    const float* W_ih  = (const float*)d_in[6];
    const float* W_hh  = (const float*)d_in[7];
    const float* b_ih  = (const float*)d_in[8];
    const float* b_hh  = (const float*)d_in[9];
    const float* W_out = (const float*)d_in[10];
    const float* b_out = (const float*)d_in[11];
    float* out = (float*)d_out;

    size_t off = 0;
    char* wsb = (char*)d_ws;
    auto alloc = [&](size_t bytes) -> void* {
        void* p = wsb + off;
        off = (off + bytes + 255) & ~(size_t)255;
        return p;
    };
    int*   deg       = (int*)alloc(N_NODES * 4);
    int*   cursor    = (int*)alloc(N_NODES * 4);
    int*   row_start = (int*)alloc((N_NODES + 1) * 4);
    float* dinv      = (float*)alloc(N_NODES * 4);
    float* self_norm = (float*)alloc(N_NODES * 4);
    float* W2T       = (float*)alloc(HIDDEN * HIDDEN * 4);
    int*   csr_src   = (int*)alloc(N_EDGES * 4);
    float* csr_norm  = (float*)alloc(N_EDGES * 4);

    size_t bigBatched = (size_t)TOTAL_ROWS * HIDDEN * 4;
    bool batched = (ws_size - off) >= 4 * bigBatched + 1024;
    int rows = batched ? TOTAL_ROWS : N_NODES;
    size_t big = (size_t)rows * HIDDEN * 4;
    float* Hbuf = (float*)alloc(big);
    float* Zbuf = (float*)alloc(big);
    float* hA   = (float*)alloc(big);
    float* hB   = (float*)alloc(big);

    // graph prep
    hipMemsetAsync(deg, 0, N_NODES * 4, stream);
    hipMemsetAsync(cursor, 0, N_NODES * 4, stream);
    k_deg<<<(N_EDGES + 255) / 256, 256, 0, stream>>>(ei, deg);
    k_scan<<<1, 1024, 0, stream>>>(deg, row_start);
    k_dinv<<<(N_NODES + 255) / 256, 256, 0, stream>>>(deg, dinv, self_norm);
    k_fill<<<(N_EDGES + 255) / 256, 256, 0, stream>>>(ei, row_start, cursor, dinv, csr_src, csr_norm);
    k_w2t<<<(HIDDEN * HIDDEN + 255) / 256, 256, 0, stream>>>(W2, W2T);

    int rounds = batched ? 1 : NDAYS;
    for (int dd = 0; dd < rounds; ++dd) {
        int rowOffset = batched ? 0 : dd * N_NODES;
        hipMemsetAsync(hA, 0, big, stream);
        float* hin = hA;
        float* hout = hB;
        dim3 g2((rows + 63) / 64, 2);
        for (int t = 0; t < LOOKBACK; ++t) {
            k_gcn1<<<((size_t)rows * 64 + 255) / 256, 256, 0, stream>>>(x, W1, Hbuf, rowOffset, rows, t);
            k_agg<<<(rows + 3) / 4, 256, 0, stream>>>(Hbuf, Zbuf, b1, row_start, csr_src, csr_norm,
                                                      self_norm, rowOffset, rows);
            k_gemm2<<<g2, 256, 0, stream>>>(Zbuf, W2T, Hbuf, rows);
            k_agg<<<(rows + 3) / 4, 256, 0, stream>>>(Hbuf, Zbuf, b2, row_start, csr_src, csr_norm,
                                                      self_norm, rowOffset, rows);
            k_gru<<<g2, 256, 0, stream>>>(Zbuf, hin, hout, W_ih, W_hh, b_ih, b_hh, rows);
            float* tmp = hin; hin = hout; hout = tmp;
        }
        k_out<<<(rows + 3) / 4, 256, 0, stream>>>(hin, W_out, b_out, out, rowOffset, rows);
    }
}

// Round 5
// 3411.569 us; speedup vs baseline: 1.6644x; 1.6644x over previous
//
#include <hip/hip_runtime.h>
#include <cstddef>
#include <cstdint>

#define N_NODES 20000
#define N_EDGES 320000
#define NDAYS 4
#define LOOKBACK 7
#define NFEAT 5
#define HIDDEN 128
#define TOTAL_ROWS (NDAYS * N_NODES)

typedef short bf8 __attribute__((ext_vector_type(8)));
typedef float fx4 __attribute__((ext_vector_type(4)));

__device__ __forceinline__ float bflo(unsigned int u) {
    union { unsigned int u; float f; } v; v.u = u << 16; return v.f;
}
__device__ __forceinline__ float bfhi(unsigned int u) {
    union { unsigned int u; float f; } v; v.u = u & 0xffff0000u; return v.f;
}
__device__ __forceinline__ unsigned short f2bf(float f) {
    union { float f; unsigned int u; } v; v.f = f;
    unsigned int u = v.u + 0x7fffu + ((v.u >> 16) & 1u);
    return (unsigned short)(u >> 16);
}
__device__ __forceinline__ unsigned int packbf(float a, float b) {
    return (unsigned int)f2bf(a) | ((unsigned int)f2bf(b) << 16);
}
__device__ __forceinline__ float sigm(float v) { return 1.0f / (1.0f + __expf(-v)); }
__device__ __forceinline__ float ftanh(float v) {
    float e2 = __expf(2.0f * v);
    return (e2 - 1.0f) / (e2 + 1.0f);
}

// ---------------- graph preprocessing ----------------

__global__ __launch_bounds__(256) void k_deg(const int* __restrict__ ei, int* __restrict__ deg) {
    int e = blockIdx.x * 256 + threadIdx.x;
    if (e < N_EDGES) atomicAdd(&deg[ei[N_EDGES + e]], 1);
}

__global__ __launch_bounds__(1024) void k_scan(const int* __restrict__ deg, int* __restrict__ row_start) {
    __shared__ int part[1024];
    int tid = threadIdx.x;
    const int chunk = (N_NODES + 1023) / 1024;  // 20
    int i0 = tid * chunk;
    int i1 = min(i0 + chunk, N_NODES);
    int s = 0;
    for (int i = i0; i < i1; ++i) s += deg[i];
    part[tid] = s;
    __syncthreads();
    for (int d = 1; d < 1024; d <<= 1) {
        int v = (tid >= d) ? part[tid - d] : 0;
        __syncthreads();
        part[tid] += v;
        __syncthreads();
    }
    int base = part[tid] - s;  // exclusive prefix
    for (int i = i0; i < i1; ++i) { row_start[i] = base; base += deg[i]; }
    if (tid == 1023) row_start[N_NODES] = part[1023];
}

__global__ __launch_bounds__(256) void k_dinv(const int* __restrict__ deg, float* __restrict__ dinv,
                                              float* __restrict__ self_norm) {
    int i = blockIdx.x * 256 + threadIdx.x;
    if (i >= N_NODES) return;
    float d = (float)(deg[i] + 1);
    dinv[i] = 1.0f / sqrtf(d);
    self_norm[i] = 1.0f / d;
}

__global__ __launch_bounds__(256) void k_fill(const int* __restrict__ ei, const int* __restrict__ row_start,
                                              int* __restrict__ cursor, const float* __restrict__ dinv,
                                              int* __restrict__ csr_src, float* __restrict__ csr_norm) {
    int e = blockIdx.x * 256 + threadIdx.x;
    if (e >= N_EDGES) return;
    int s = ei[e], d = ei[N_EDGES + e];
    int pos = row_start[d] + atomicAdd(&cursor[d], 1);
    csr_src[pos] = s;
    csr_norm[pos] = dinv[s] * dinv[d];
}

// W2T_bf[c][k] = bf16(W2[k][c])  (so B rows are k-contiguous)
__global__ __launch_bounds__(256) void k_w2t(const float* __restrict__ W2, unsigned short* __restrict__ W2T) {
    int idx = blockIdx.x * 256 + threadIdx.x;
    if (idx >= HIDDEN * HIDDEN) return;
    int k = idx >> 7, c = idx & 127;
    W2T[c * HIDDEN + k] = f2bf(W2[k * HIDDEN + c]);
}

__global__ __launch_bounds__(256) void k_cast(const float* __restrict__ src, unsigned short* __restrict__ dst, int n) {
    int i = blockIdx.x * 256 + threadIdx.x;
    if (i < n) dst[i] = f2bf(src[i]);
}

// b_fold[j] = b_ih[j] + b_hh[j] for r,z gates (j<256); b_ih[j] only for n gate
__global__ __launch_bounds__(256) void k_bfold(const float* __restrict__ b_ih, const float* __restrict__ b_hh,
                                               float* __restrict__ b_fold) {
    int i = blockIdx.x * 256 + threadIdx.x;
    if (i < 3 * HIDDEN) b_fold[i] = b_ih[i] + (i < 2 * HIDDEN ? b_hh[i] : 0.0f);
}

// ---------------- GCN layer 1: H1 = x_t @ W1 (bf16 out) ----------------

__global__ __launch_bounds__(256) void k_gcn1(const float* __restrict__ x, const float* __restrict__ W1,
                                              unsigned int* __restrict__ H, int rowOffset, int nrows, int t) {
    int idx = blockIdx.x * 256 + threadIdx.x;
    int r = idx >> 6;
    if (r >= nrows) return;
    int lane = idx & 63;
    int c = lane * 2;
    const float* xp = x + (size_t)(rowOffset + r) * (LOOKBACK * NFEAT) + t * NFEAT;
    float x0 = xp[0], x1 = xp[1], x2 = xp[2], x3 = xp[3], x4 = xp[4];
    float a0 = x0 * W1[c] + x1 * W1[128 + c] + x2 * W1[256 + c] + x3 * W1[384 + c] + x4 * W1[512 + c];
    float a1 = x0 * W1[c + 1] + x1 * W1[129 + c] + x2 * W1[257 + c] + x3 * W1[385 + c] + x4 * W1[513 + c];
    H[(size_t)r * 64 + lane] = packbf(a0, a1);
}

// ---------------- GCN aggregation (bf16 in/out): Z = relu(agg + self + b) ----------------

__global__ __launch_bounds__(256) void k_agg(const unsigned int* __restrict__ H, unsigned int* __restrict__ Z,
                                             const float* __restrict__ bias,
                                             const int* __restrict__ row_start, const int* __restrict__ csr_src,
                                             const float* __restrict__ csr_norm, const float* __restrict__ self_norm,
                                             int rowOffset, int nrows) {
    int r = blockIdx.x * 4 + (threadIdx.x >> 6);
    if (r >= nrows) return;
    int lane = threadIdx.x & 63;
    int g = rowOffset + r;
    int n = g % N_NODES;
    int dayLocalBase = (g - n) - rowOffset;
    unsigned int su = H[(size_t)r * 64 + lane];
    float sn = self_norm[n];
    float acc0 = bflo(su) * sn, acc1 = bfhi(su) * sn;
    int e1 = row_start[n + 1];
    for (int e = row_start[n]; e < e1; ++e) {
        int s = csr_src[e];
        float w = csr_norm[e];
        unsigned int hv = H[(size_t)(dayLocalBase + s) * 64 + lane];
        acc0 += w * bflo(hv);
        acc1 += w * bfhi(hv);
    }
    float2 b = ((const float2*)bias)[lane];
    acc0 = fmaxf(acc0 + b.x, 0.0f);
    acc1 = fmaxf(acc1 + b.y, 0.0f);
    Z[(size_t)r * 64 + lane] = packbf(acc0, acc1);
}

// ---------------- MFMA GEMM: H2 = Z1 @ W2  (A[r][k] bf16, B=W2T[c][k] bf16, out bf16 row-major) ----------------

__global__ __launch_bounds__(256) void k_gemm_h2(const unsigned short* __restrict__ A,
                                                 const unsigned short* __restrict__ W,
                                                 unsigned short* __restrict__ Out, int rows) {
    int tid = threadIdx.x, w = tid >> 6, l = tid & 63, lr = l & 15, lk = l >> 4;
    int rblk = blockIdx.x * 64;
    int rowA = rblk + w * 16 + lr;
    bool okA = rowA < rows;
    const bf8* Ap = (const bf8*)(A + (size_t)rowA * HIDDEN);
    const bf8* Bp = (const bf8*)W;
    fx4 acc[8];
#pragma unroll
    for (int n = 0; n < 8; ++n) acc[n] = (fx4){0.f, 0.f, 0.f, 0.f};
#pragma unroll
    for (int ks = 0; ks < 4; ++ks) {
        bf8 a = okA ? Ap[4 * ks + lk] : (bf8){0, 0, 0, 0, 0, 0, 0, 0};
#pragma unroll
        for (int n = 0; n < 8; ++n) {
            bf8 b = Bp[(size_t)(16 * n + lr) * 16 + 4 * ks + lk];
            acc[n] = __builtin_amdgcn_mfma_f32_16x16x32_bf16(a, b, acc[n], 0, 0, 0);
        }
    }
#pragma unroll
    for (int n = 0; n < 8; ++n)
#pragma unroll
        for (int r = 0; r < 4; ++r) {
            int row = rblk + w * 16 + lk * 4 + r;
            if (row < rows) Out[(size_t)row * HIDDEN + 16 * n + lr] = f2bf(acc[n][r]);
        }
}

// ---------------- MFMA GEMM: gi = Z2 @ W_ih^T + b_fold, stored bf16 in fragment layout ----------------

__global__ __launch_bounds__(256) void k_gi(const unsigned short* __restrict__ A,
                                            const unsigned short* __restrict__ W,
                                            const float* __restrict__ bfold,
                                            unsigned short* __restrict__ giF, int rows) {
    int tid = threadIdx.x, w = tid >> 6, l = tid & 63, lr = l & 15, lk = l >> 4;
    int rblk = blockIdx.x * 64;
    int rowA = rblk + w * 16 + lr;
    bool okA = rowA < rows;
    const bf8* Ap = (const bf8*)(A + (size_t)rowA * HIDDEN);
    const bf8* Bp = (const bf8*)W;
    fx4 acc[24];
#pragma unroll
    for (int n = 0; n < 24; ++n) acc[n] = (fx4){0.f, 0.f, 0.f, 0.f};
#pragma unroll
    for (int ks = 0; ks < 4; ++ks) {
        bf8 a = okA ? Ap[4 * ks + lk] : (bf8){0, 0, 0, 0, 0, 0, 0, 0};
#pragma unroll
        for (int n = 0; n < 24; ++n) {
            bf8 b = Bp[(size_t)(16 * n + lr) * 16 + 4 * ks + lk];
            acc[n] = __builtin_amdgcn_mfma_f32_16x16x32_bf16(a, b, acc[n], 0, 0, 0);
        }
    }
    size_t tbase = ((size_t)blockIdx.x * 4 + w) * 24;
#pragma unroll
    for (int n = 0; n < 24; ++n) {
        float bc = bfold[16 * n + lr];
        uint2 v;
        v.x = packbf(acc[n][0] + bc, acc[n][1] + bc);
        v.y = packbf(acc[n][2] + bc, acc[n][3] + bc);
        ((uint2*)giF)[(tbase + n) * 64 + l] = v;
    }
}

// ---------------- sequential GRU step: gh = h @ W_hh^T, fuse gates, update h in place ----------------

__global__ __launch_bounds__(256) void k_gruseq(unsigned short* Hbf,  // bf16 h (A operand, also updated)
                                                const unsigned short* __restrict__ Whh,
                                                const unsigned short* __restrict__ giF,
                                                const float* __restrict__ b_hh,
                                                float* Hf, int rows) {
    int tid = threadIdx.x, w = tid >> 6, l = tid & 63, lr = l & 15, lk = l >> 4;
    int rblk = blockIdx.x * 64;
    int rowA = rblk + w * 16 + lr;
    bool okA = rowA < rows;
    const bf8* Ap = (const bf8*)(Hbf + (size_t)rowA * HIDDEN);
    const bf8* Bp = (const bf8*)Whh;
    fx4 acc[24];
#pragma unroll
    for (int n = 0; n < 24; ++n) acc[n] = (fx4){0.f, 0.f, 0.f, 0.f};
#pragma unroll
    for (int ks = 0; ks < 4; ++ks) {
        bf8 a = okA ? Ap[4 * ks + lk] : (bf8){0, 0, 0, 0, 0, 0, 0, 0};
#pragma unroll
        for (int n = 0; n < 24; ++n) {
            bf8 b = Bp[(size_t)(16 * n + lr) * 16 + 4 * ks + lk];
            acc[n] = __builtin_amdgcn_mfma_f32_16x16x32_bf16(a, b, acc[n], 0, 0, 0);
        }
    }
    size_t tbase = ((size_t)blockIdx.x * 4 + w) * 24;
    const uint2* giF2 = (const uint2*)giF;
#pragma unroll
    for (int n = 0; n < 8; ++n) {
        int c = 16 * n + lr;
        float bhn = b_hh[2 * HIDDEN + c];
        uint2 vr = giF2[(tbase + n) * 64 + l];
        uint2 vz = giF2[(tbase + n + 8) * 64 + l];
        uint2 vn = giF2[(tbase + n + 16) * 64 + l];
        float gir[4] = {bflo(vr.x), bfhi(vr.x), bflo(vr.y), bfhi(vr.y)};
        float giz[4] = {bflo(vz.x), bfhi(vz.x), bflo(vz.y), bfhi(vz.y)};
        float gin[4] = {bflo(vn.x), bfhi(vn.x), bflo(vn.y), bfhi(vn.y)};
#pragma unroll
        for (int r = 0; r < 4; ++r) {
            int row = rblk + w * 16 + lk * 4 + r;
            if (row >= rows) continue;
            size_t hidx = (size_t)row * HIDDEN + c;
            float hold = Hf[hidx];
            float rr = sigm(acc[n][r] + gir[r]);
            float zz = sigm(acc[n + 8][r] + giz[r]);
            float nn = ftanh(gin[r] + rr * (acc[n + 16][r] + bhn));
            float hnew = (1.0f - zz) * nn + zz * hold;
            Hf[hidx] = hnew;
            Hbf[hidx] = f2bf(hnew);
        }
    }
}

// ---------------- output head: softmax(h @ W_out + b_out) ----------------

__global__ __launch_bounds__(256) void k_out(const float* __restrict__ Hc, const float* __restrict__ Wo,
                                             const float* __restrict__ bo, float* __restrict__ out,
                                             int rowOffset, int nrows) {
    int r = blockIdx.x * 4 + (threadIdx.x >> 6);
    if (r >= nrows) return;
    int lane = threadIdx.x & 63;
    float2 hv = ((const float2*)(Hc + (size_t)r * HIDDEN))[lane];
    float l[5];
#pragma unroll
    for (int j = 0; j < 5; ++j) {
        float p = hv.x * Wo[(2 * lane) * 5 + j] + hv.y * Wo[(2 * lane + 1) * 5 + j];
#pragma unroll
        for (int s = 1; s < 64; s <<= 1) p += __shfl_xor(p, s);
        l[j] = p + bo[j];
    }
    float m = fmaxf(fmaxf(fmaxf(l[0], l[1]), fmaxf(l[2], l[3])), l[4]);
    float e0 = expf(l[0] - m), e1 = expf(l[1] - m), e2 = expf(l[2] - m), e3 = expf(l[3] - m), e4 = expf(l[4] - m);
    float inv = 1.0f / (e0 + e1 + e2 + e3 + e4);
    if (lane < 5) {
        float ej = lane == 0 ? e0 : lane == 1 ? e1 : lane == 2 ? e2 : lane == 3 ? e3 : e4;
        out[(size_t)(rowOffset + r) * 5 + lane] = ej * inv;
    }
}

// ---------------- launch ----------------

extern "C" void kernel_launch(void* const* d_in, const int* in_sizes, int n_in,
                              void* d_out, int out_size, void* d_ws, size_t ws_size,
                              hipStream_t stream) {
    const float* x     = (const float*)d_in[0];
    const int*   ei    = (const int*)d_in[1];
    const float* W1    = (const float*)d_in[2];
    const float* b1    = (const float*)d_in[3];
    const float* W2    = (const float*)d_in[4];
    const float* b2    = (const float*)d_in[5];
    const float* W_ih  = (const float*)d_in[6];
    const float* W_hh  = (const float*)d_in[7];
    const float* b_ih  = (const float*)d_in[8];
    const float* b_hh  = (const float*)d_in[9];
    const float* W_out = (const float*)d_in[10];
    const float* b_out = (const float*)d_in[11];
    float* out = (float*)d_out;

    size_t off = 0;
    char* wsb = (char*)d_ws;
    auto alloc = [&](size_t bytes) -> void* {
        void* p = wsb + off;
        off = (off + bytes + 255) & ~(size_t)255;
        return p;
    };
    int*            deg       = (int*)alloc(N_NODES * 4);
    int*            cursor    = (int*)alloc(N_NODES * 4);
    int*            row_start = (int*)alloc((N_NODES + 1) * 4);
    float*          dinv      = (float*)alloc(N_NODES * 4);
    float*          self_norm = (float*)alloc(N_NODES * 4);
    unsigned short* W2T_bf    = (unsigned short*)alloc(HIDDEN * HIDDEN * 2);
    unsigned short* Wih_bf    = (unsigned short*)alloc(3 * HIDDEN * HIDDEN * 2);
    unsigned short* Whh_bf    = (unsigned short*)alloc(3 * HIDDEN * HIDDEN * 2);
    float*          b_fold    = (float*)alloc(3 * HIDDEN * 4);
    int*            csr_src   = (int*)alloc(N_EDGES * 4);
    float*          csr_norm  = (float*)alloc(N_EDGES * 4);

    // per-row activation bytes: H1,Z1,H2,Z2 bf16 (4*256) + h_f32 (512) + h_bf (256)
    // giF sized by block count (nblk*4 waves*24 tiles*512B)
    size_t prep_off = off;
    auto need = [&](int rows) -> size_t {
        size_t nblk = (size_t)(rows + 63) / 64;
        return prep_off + (size_t)rows * (4 * 256 + 512 + 256) + nblk * 49152 + 8 * 256;
    };
    bool batched = need(TOTAL_ROWS) <= ws_size;
    int rows = batched ? TOTAL_ROWS : N_NODES;
    size_t nblk = (size_t)(rows + 63) / 64;
    size_t actB = (size_t)rows * HIDDEN * 2;  // bf16 activation buffer

    unsigned short* H1  = (unsigned short*)alloc(actB);
    unsigned short* Z1  = (unsigned short*)alloc(actB);
    unsigned short* H2  = (unsigned short*)alloc(actB);
    unsigned short* Z2  = (unsigned short*)alloc(actB);
    unsigned short* giF = (unsigned short*)alloc(nblk * 49152);
    float*          h_f = (float*)alloc((size_t)rows * HIDDEN * 4);
    unsigned short* h_b = (unsigned short*)alloc(actB);

    // graph + weight prep
    hipMemsetAsync(deg, 0, N_NODES * 4, stream);
    hipMemsetAsync(cursor, 0, N_NODES * 4, stream);
    k_deg<<<(N_EDGES + 255) / 256, 256, 0, stream>>>(ei, deg);
    k_scan<<<1, 1024, 0, stream>>>(deg, row_start);
    k_dinv<<<(N_NODES + 255) / 256, 256, 0, stream>>>(deg, dinv, self_norm);
    k_fill<<<(N_EDGES + 255) / 256, 256, 0, stream>>>(ei, row_start, cursor, dinv, csr_src, csr_norm);
    k_w2t<<<(HIDDEN * HIDDEN + 255) / 256, 256, 0, stream>>>(W2, W2T_bf);
    k_cast<<<(3 * HIDDEN * HIDDEN + 255) / 256, 256, 0, stream>>>(W_ih, Wih_bf, 3 * HIDDEN * HIDDEN);
    k_cast<<<(3 * HIDDEN * HIDDEN + 255) / 256, 256, 0, stream>>>(W_hh, Whh_bf, 3 * HIDDEN * HIDDEN);
    k_bfold<<<2, 256, 0, stream>>>(b_ih, b_hh, b_fold);

    int rounds = batched ? 1 : NDAYS;
    for (int dd = 0; dd < rounds; ++dd) {
        int rowOffset = batched ? 0 : dd * N_NODES;
        hipMemsetAsync(h_f, 0, (size_t)rows * HIDDEN * 4, stream);
        hipMemsetAsync(h_b, 0, actB, stream);
        for (int t = 0; t < LOOKBACK; ++t) {
            k_gcn1<<<(rows + 3) / 4, 256, 0, stream>>>(x, W1, (unsigned int*)H1, rowOffset, rows, t);
            k_agg<<<(rows + 3) / 4, 256, 0, stream>>>((unsigned int*)H1, (unsigned int*)Z1, b1,
                                                      row_start, csr_src, csr_norm, self_norm, rowOffset, rows);
            k_gemm_h2<<<(unsigned)nblk, 256, 0, stream>>>(Z1, W2T_bf, H2, rows);
            k_agg<<<(rows + 3) / 4, 256, 0, stream>>>((unsigned int*)H2, (unsigned int*)Z2, b2,
                                                      row_start, csr_src, csr_norm, self_norm, rowOffset, rows);
            k_gi<<<(unsigned)nblk, 256, 0, stream>>>(Z2, Wih_bf, b_fold, giF, rows);
            k_gruseq<<<(unsigned)nblk, 256, 0, stream>>>(h_b, Whh_bf, giF, b_hh, h_f, rows);
        }
        k_out<<<(rows + 3) / 4, 256, 0, stream>>>(h_f, W_out, b_out, out, rowOffset, rows);
    }
}

// Round 6
// 2337.666 us; speedup vs baseline: 2.4290x; 1.4594x over previous
//
#include <hip/hip_runtime.h>
#include <cstddef>
#include <cstdint>

#define N_NODES 20000
#define N_EDGES 320000
#define NDAYS 4
#define LOOKBACK 7
#define NFEAT 5
#define XROW (LOOKBACK * NFEAT)  // 35
#define HIDDEN 128
#define TOTAL_ROWS (NDAYS * N_NODES)

typedef short bf8 __attribute__((ext_vector_type(8)));
typedef float fx4 __attribute__((ext_vector_type(4)));

__device__ __forceinline__ float bflo(unsigned int u) {
    union { unsigned int u; float f; } v; v.u = u << 16; return v.f;
}
__device__ __forceinline__ float bfhi(unsigned int u) {
    union { unsigned int u; float f; } v; v.u = u & 0xffff0000u; return v.f;
}
__device__ __forceinline__ unsigned short f2bf(float f) {
    union { float f; unsigned int u; } v; v.f = f;
    unsigned int u = v.u + 0x7fffu + ((v.u >> 16) & 1u);
    return (unsigned short)(u >> 16);
}
__device__ __forceinline__ unsigned int packbf(float a, float b) {
    return (unsigned int)f2bf(a) | ((unsigned int)f2bf(b) << 16);
}
__device__ __forceinline__ float sigm(float v) { return 1.0f / (1.0f + __expf(-v)); }
__device__ __forceinline__ float ftanh(float v) {
    float e2 = __expf(2.0f * v);
    return (e2 - 1.0f) / (e2 + 1.0f);
}

// ---------------- graph preprocessing ----------------

__global__ __launch_bounds__(256) void k_deg(const int* __restrict__ ei, int* __restrict__ deg) {
    int e = blockIdx.x * 256 + threadIdx.x;
    if (e < N_EDGES) atomicAdd(&deg[ei[N_EDGES + e]], 1);
}

__global__ __launch_bounds__(1024) void k_scan(const int* __restrict__ deg, int* __restrict__ row_start) {
    __shared__ int part[1024];
    int tid = threadIdx.x;
    const int chunk = (N_NODES + 1023) / 1024;  // 20
    int i0 = tid * chunk;
    int i1 = min(i0 + chunk, N_NODES);
    int s = 0;
    for (int i = i0; i < i1; ++i) s += deg[i];
    part[tid] = s;
    __syncthreads();
    for (int d = 1; d < 1024; d <<= 1) {
        int v = (tid >= d) ? part[tid - d] : 0;
        __syncthreads();
        part[tid] += v;
        __syncthreads();
    }
    int base = part[tid] - s;  // exclusive prefix
    for (int i = i0; i < i1; ++i) { row_start[i] = base; base += deg[i]; }
    if (tid == 1023) row_start[N_NODES] = part[1023];
}

__global__ __launch_bounds__(256) void k_dinv(const int* __restrict__ deg, float* __restrict__ dinv,
                                              float* __restrict__ self_norm) {
    int i = blockIdx.x * 256 + threadIdx.x;
    if (i >= N_NODES) return;
    float d = (float)(deg[i] + 1);
    dinv[i] = 1.0f / sqrtf(d);
    self_norm[i] = 1.0f / d;
}

__global__ __launch_bounds__(256) void k_fill(const int* __restrict__ ei, const int* __restrict__ row_start,
                                              int* __restrict__ cursor, const float* __restrict__ dinv,
                                              int* __restrict__ csr_src, float* __restrict__ csr_norm) {
    int e = blockIdx.x * 256 + threadIdx.x;
    if (e >= N_EDGES) return;
    int s = ei[e], d = ei[N_EDGES + e];
    int pos = row_start[d] + atomicAdd(&cursor[d], 1);
    csr_src[pos] = s;
    csr_norm[pos] = dinv[s] * dinv[d];
}

// W2T_bf[c][k] = bf16(W2[k][c])
__global__ __launch_bounds__(256) void k_w2t(const float* __restrict__ W2, unsigned short* __restrict__ W2T) {
    int idx = blockIdx.x * 256 + threadIdx.x;
    if (idx >= HIDDEN * HIDDEN) return;
    int k = idx >> 7, c = idx & 127;
    W2T[c * HIDDEN + k] = f2bf(W2[k * HIDDEN + c]);
}

__global__ __launch_bounds__(256) void k_cast(const float* __restrict__ src, unsigned short* __restrict__ dst, int n) {
    int i = blockIdx.x * 256 + threadIdx.x;
    if (i < n) dst[i] = f2bf(src[i]);
}

// b_fold[j] = b_ih[j] + b_hh[j] for r,z gates (j<256); b_ih[j] only for n gate
__global__ __launch_bounds__(256) void k_bfold(const float* __restrict__ b_ih, const float* __restrict__ b_hh,
                                               float* __restrict__ b_fold) {
    int i = blockIdx.x * 256 + threadIdx.x;
    if (i < 3 * HIDDEN) b_fold[i] = b_ih[i] + (i < 2 * HIDDEN ? b_hh[i] : 0.0f);
}

// ---------------- feature-space aggregation (once, all days/timesteps): xa = agg(x) ----------------
// agg(x @ W1) == agg(x) @ W1  (GCN layer-1 is linear before ReLU)

__global__ __launch_bounds__(256) void k_aggx(const float* __restrict__ x, float* __restrict__ xa,
                                              const int* __restrict__ row_start, const int* __restrict__ csr_src,
                                              const float* __restrict__ csr_norm,
                                              const float* __restrict__ self_norm) {
    int g = blockIdx.x * 4 + (threadIdx.x >> 6);
    if (g >= TOTAL_ROWS) return;
    int lane = threadIdx.x & 63;
    if (lane >= XROW) return;
    int n = g % N_NODES;
    int dayBase = g - n;
    float acc = x[(size_t)g * XROW + lane] * self_norm[n];
    int e1 = row_start[n + 1];
    for (int e = row_start[n]; e < e1; ++e) {
        int s = csr_src[e];
        float w = csr_norm[e];
        acc += w * x[(size_t)(dayBase + s) * XROW + lane];
    }
    xa[(size_t)g * XROW + lane] = acc;
}

// ---------------- Z1 = relu(xa[:, t, :] @ W1 + b1)  (bf16 out) ----------------

__global__ __launch_bounds__(256) void k_z1(const float* __restrict__ xa, const float* __restrict__ W1,
                                            const float* __restrict__ b1,
                                            unsigned int* __restrict__ Z, int rowOffset, int nrows, int t) {
    int idx = blockIdx.x * 256 + threadIdx.x;
    int r = idx >> 6;
    if (r >= nrows) return;
    int lane = idx & 63;
    int c = lane * 2;
    const float* xp = xa + (size_t)(rowOffset + r) * XROW + t * NFEAT;
    float x0 = xp[0], x1 = xp[1], x2 = xp[2], x3 = xp[3], x4 = xp[4];
    float a0 = x0 * W1[c] + x1 * W1[128 + c] + x2 * W1[256 + c] + x3 * W1[384 + c] + x4 * W1[512 + c];
    float a1 = x0 * W1[c + 1] + x1 * W1[129 + c] + x2 * W1[257 + c] + x3 * W1[385 + c] + x4 * W1[513 + c];
    a0 = fmaxf(a0 + b1[c], 0.0f);
    a1 = fmaxf(a1 + b1[c + 1], 0.0f);
    Z[(size_t)r * 64 + lane] = packbf(a0, a1);
}

// ---------------- hidden-space aggregation (bf16 in/out): Z = relu(agg + self + b) ----------------

__global__ __launch_bounds__(256) void k_agg(const unsigned int* __restrict__ H, unsigned int* __restrict__ Z,
                                             const float* __restrict__ bias,
                                             const int* __restrict__ row_start, const int* __restrict__ csr_src,
                                             const float* __restrict__ csr_norm, const float* __restrict__ self_norm,
                                             int rowOffset, int nrows) {
    int r = blockIdx.x * 4 + (threadIdx.x >> 6);
    if (r >= nrows) return;
    int lane = threadIdx.x & 63;
    int g = rowOffset + r;
    int n = g % N_NODES;
    int dayLocalBase = (g - n) - rowOffset;
    unsigned int su = H[(size_t)r * 64 + lane];
    float sn = self_norm[n];
    float acc0 = bflo(su) * sn, acc1 = bfhi(su) * sn;
    int e1 = row_start[n + 1];
    for (int e = row_start[n]; e < e1; ++e) {
        int s = csr_src[e];
        float w = csr_norm[e];
        unsigned int hv = H[(size_t)(dayLocalBase + s) * 64 + lane];
        acc0 += w * bflo(hv);
        acc1 += w * bfhi(hv);
    }
    float2 b = ((const float2*)bias)[lane];
    acc0 = fmaxf(acc0 + b.x, 0.0f);
    acc1 = fmaxf(acc1 + b.y, 0.0f);
    Z[(size_t)r * 64 + lane] = packbf(acc0, acc1);
}

// ---------------- MFMA GEMM: H2 = Z1 @ W2  (out bf16 row-major) ----------------

__global__ __launch_bounds__(256) void k_gemm_h2(const unsigned short* __restrict__ A,
                                                 const unsigned short* __restrict__ W,
                                                 unsigned short* __restrict__ Out, int rows) {
    int tid = threadIdx.x, w = tid >> 6, l = tid & 63, lr = l & 15, lk = l >> 4;
    int rblk = blockIdx.x * 64;
    int rowA = rblk + w * 16 + lr;
    bool okA = rowA < rows;
    const bf8* Ap = (const bf8*)(A + (size_t)rowA * HIDDEN);
    const bf8* Bp = (const bf8*)W;
    fx4 acc[8];
#pragma unroll
    for (int n = 0; n < 8; ++n) acc[n] = (fx4){0.f, 0.f, 0.f, 0.f};
#pragma unroll
    for (int ks = 0; ks < 4; ++ks) {
        bf8 a = okA ? Ap[4 * ks + lk] : (bf8){0, 0, 0, 0, 0, 0, 0, 0};
#pragma unroll
        for (int n = 0; n < 8; ++n) {
            bf8 b = Bp[(size_t)(16 * n + lr) * 16 + 4 * ks + lk];
            acc[n] = __builtin_amdgcn_mfma_f32_16x16x32_bf16(a, b, acc[n], 0, 0, 0);
        }
    }
#pragma unroll
    for (int n = 0; n < 8; ++n)
#pragma unroll
        for (int r = 0; r < 4; ++r) {
            int row = rblk + w * 16 + lk * 4 + r;
            if (row < rows) Out[(size_t)row * HIDDEN + 16 * n + lr] = f2bf(acc[n][r]);
        }
}

// ---------------- fused GRU: gi = Z2@W_ih^T, gh = h@W_hh^T, gates, h update (in place, f32 h) ----------------
// 8 waves: (wr = w>>1) row-group, (wc = w&1) col-half. Each wave: 16 rows x 192 cols (both GEMMs).

__global__ __launch_bounds__(512, 2) void k_grufused(const unsigned short* __restrict__ Z2,
                                                     float* Hf,
                                                     const unsigned short* __restrict__ Wih,
                                                     const unsigned short* __restrict__ Whh,
                                                     const float* __restrict__ bfold,
                                                     const float* __restrict__ bhh, int rows) {
    int tid = threadIdx.x, w = tid >> 6, l = tid & 63, lr = l & 15, lk = l >> 4;
    int wr = w >> 1, wc = w & 1;
    int rblk = blockIdx.x * 64;
    int rowA = rblk + wr * 16 + lr;
    bool okA = rowA < rows;
    const bf8* Az = (const bf8*)(Z2 + (size_t)rowA * HIDDEN);
    const float4* Ah4 = (const float4*)(Hf + (size_t)rowA * HIDDEN);
    const bf8* Bi = (const bf8*)Wih;
    const bf8* Bh = (const bf8*)Whh;
    fx4 ai[3][4], ah[3][4];
#pragma unroll
    for (int g = 0; g < 3; ++g)
#pragma unroll
        for (int q = 0; q < 4; ++q) { ai[g][q] = (fx4){0.f, 0.f, 0.f, 0.f}; ah[g][q] = (fx4){0.f, 0.f, 0.f, 0.f}; }

#pragma unroll
    for (int ks = 0; ks < 4; ++ks) {
        bf8 az = okA ? Az[4 * ks + lk] : (bf8){0, 0, 0, 0, 0, 0, 0, 0};
        bf8 azh = (bf8){0, 0, 0, 0, 0, 0, 0, 0};
        if (okA) {
            float4 u0 = Ah4[8 * ks + 2 * lk];
            float4 u1 = Ah4[8 * ks + 2 * lk + 1];
            azh[0] = (short)f2bf(u0.x); azh[1] = (short)f2bf(u0.y);
            azh[2] = (short)f2bf(u0.z); azh[3] = (short)f2bf(u0.w);
            azh[4] = (short)f2bf(u1.x); azh[5] = (short)f2bf(u1.y);
            azh[6] = (short)f2bf(u1.z); azh[7] = (short)f2bf(u1.w);
        }
#pragma unroll
        for (int g = 0; g < 3; ++g)
#pragma unroll
            for (int q = 0; q < 4; ++q) {
                int nt = g * 8 + wc * 4 + q;  // tile index into 24 output col-tiles (384 cols)
                bf8 bi = Bi[(size_t)(16 * nt + lr) * 16 + 4 * ks + lk];
                ai[g][q] = __builtin_amdgcn_mfma_f32_16x16x32_bf16(az, bi, ai[g][q], 0, 0, 0);
                bf8 bh = Bh[(size_t)(16 * nt + lr) * 16 + 4 * ks + lk];
                ah[g][q] = __builtin_amdgcn_mfma_f32_16x16x32_bf16(azh, bh, ah[g][q], 0, 0, 0);
            }
    }

    // All Hf A-reads (by both col-half waves of each row-group) must complete before epilogue writes.
    __syncthreads();

#pragma unroll
    for (int q = 0; q < 4; ++q) {
        int c = wc * 64 + 16 * q + lr;  // hidden col 0..127
        float bf_r = bfold[c], bf_z = bfold[HIDDEN + c], bf_n = bfold[2 * HIDDEN + c];
        float bh_n = bhh[2 * HIDDEN + c];
#pragma unroll
        for (int r = 0; r < 4; ++r) {
            int row = rblk + wr * 16 + lk * 4 + r;
            if (row >= rows) continue;
            size_t hidx = (size_t)row * HIDDEN + c;
            float hold = Hf[hidx];
            float rr = sigm(ai[0][q][r] + bf_r + ah[0][q][r]);
            float zz = sigm(ai[1][q][r] + bf_z + ah[1][q][r]);
            float nn = ftanh(ai[2][q][r] + bf_n + rr * (ah[2][q][r] + bh_n));
            Hf[hidx] = (1.0f - zz) * nn + zz * hold;
        }
    }
}

// ---------------- output head: softmax(h @ W_out + b_out) ----------------

__global__ __launch_bounds__(256) void k_out(const float* __restrict__ Hc, const float* __restrict__ Wo,
                                             const float* __restrict__ bo, float* __restrict__ out,
                                             int rowOffset, int nrows) {
    int r = blockIdx.x * 4 + (threadIdx.x >> 6);
    if (r >= nrows) return;
    int lane = threadIdx.x & 63;
    float2 hv = ((const float2*)(Hc + (size_t)r * HIDDEN))[lane];
    float l[5];
#pragma unroll
    for (int j = 0; j < 5; ++j) {
        float p = hv.x * Wo[(2 * lane) * 5 + j] + hv.y * Wo[(2 * lane + 1) * 5 + j];
#pragma unroll
        for (int s = 1; s < 64; s <<= 1) p += __shfl_xor(p, s);
        l[j] = p + bo[j];
    }
    float m = fmaxf(fmaxf(fmaxf(l[0], l[1]), fmaxf(l[2], l[3])), l[4]);
    float e0 = expf(l[0] - m), e1 = expf(l[1] - m), e2 = expf(l[2] - m), e3 = expf(l[3] - m), e4 = expf(l[4] - m);
    float inv = 1.0f / (e0 + e1 + e2 + e3 + e4);
    if (lane < 5) {
        float ej = lane == 0 ? e0 : lane == 1 ? e1 : lane == 2 ? e2 : lane == 3 ? e3 : e4;
        out[(size_t)(rowOffset + r) * 5 + lane] = ej * inv;
    }
}

// ---------------- launch ----------------

extern "C" void kernel_launch(void* const* d_in, const int* in_sizes, int n_in,
                              void* d_out, int out_size, void* d_ws, size_t ws_size,
                              hipStream_t stream) {
    const float* x     = (const float*)d_in[0];
    const int*   ei    = (const int*)d_in[1];
    const float* W1    = (const float*)d_in[2];
    const float* b1    = (const float*)d_in[3];
    const float* W2    = (const float*)d_in[4];
    const float* b2    = (const float*)d_in[5];
    const float* W_ih  = (const float*)d_in[6];
    const float* W_hh  = (const float*)d_in[7];
    const float* b_ih  = (const float*)d_in[8];
    const float* b_hh  = (const float*)d_in[9];
    const float* W_out = (const float*)d_in[10];
    const float* b_out = (const float*)d_in[11];
    float* out = (float*)d_out;

    size_t off = 0;
    char* wsb = (char*)d_ws;
    auto alloc = [&](size_t bytes) -> void* {
        void* p = wsb + off;
        off = (off + bytes + 255) & ~(size_t)255;
        return p;
    };
    int*            deg       = (int*)alloc(N_NODES * 4);
    int*            cursor    = (int*)alloc(N_NODES * 4);
    int*            row_start = (int*)alloc((N_NODES + 1) * 4);
    float*          dinv      = (float*)alloc(N_NODES * 4);
    float*          self_norm = (float*)alloc(N_NODES * 4);
    unsigned short* W2T_bf    = (unsigned short*)alloc(HIDDEN * HIDDEN * 2);
    unsigned short* Wih_bf    = (unsigned short*)alloc(3 * HIDDEN * HIDDEN * 2);
    unsigned short* Whh_bf    = (unsigned short*)alloc(3 * HIDDEN * HIDDEN * 2);
    float*          b_fold    = (float*)alloc(3 * HIDDEN * 4);
    int*            csr_src   = (int*)alloc(N_EDGES * 4);
    float*          csr_norm  = (float*)alloc(N_EDGES * 4);
    float*          xa        = (float*)alloc((size_t)TOTAL_ROWS * XROW * 4);  // 11.2 MB

    // per-row bytes: Z1 (256) + H2 (256) + Z2 (256) + Hf f32 (512) = 1280
    size_t prep_off = off;
    auto need = [&](int rows) -> size_t { return prep_off + (size_t)rows * 1280 + 4096; };
    bool batched = need(TOTAL_ROWS) <= ws_size;
    int rows = batched ? TOTAL_ROWS : N_NODES;
    size_t nblk = (size_t)(rows + 63) / 64;
    size_t actB = (size_t)rows * HIDDEN * 2;

    unsigned short* Z1 = (unsigned short*)alloc(actB);
    unsigned short* H2 = (unsigned short*)alloc(actB);
    unsigned short* Z2 = (unsigned short*)alloc(actB);
    float*          Hf = (float*)alloc((size_t)rows * HIDDEN * 4);

    // graph + weight prep
    hipMemsetAsync(deg, 0, N_NODES * 4, stream);
    hipMemsetAsync(cursor, 0, N_NODES * 4, stream);
    k_deg<<<(N_EDGES + 255) / 256, 256, 0, stream>>>(ei, deg);
    k_scan<<<1, 1024, 0, stream>>>(deg, row_start);
    k_dinv<<<(N_NODES + 255) / 256, 256, 0, stream>>>(deg, dinv, self_norm);
    k_fill<<<(N_EDGES + 255) / 256, 256, 0, stream>>>(ei, row_start, cursor, dinv, csr_src, csr_norm);
    k_w2t<<<(HIDDEN * HIDDEN + 255) / 256, 256, 0, stream>>>(W2, W2T_bf);
    k_cast<<<(3 * HIDDEN * HIDDEN + 255) / 256, 256, 0, stream>>>(W_ih, Wih_bf, 3 * HIDDEN * HIDDEN);
    k_cast<<<(3 * HIDDEN * HIDDEN + 255) / 256, 256, 0, stream>>>(W_hh, Whh_bf, 3 * HIDDEN * HIDDEN);
    k_bfold<<<2, 256, 0, stream>>>(b_ih, b_hh, b_fold);
    k_aggx<<<(TOTAL_ROWS + 3) / 4, 256, 0, stream>>>(x, xa, row_start, csr_src, csr_norm, self_norm);

    int rounds = batched ? 1 : NDAYS;
    for (int dd = 0; dd < rounds; ++dd) {
        int rowOffset = batched ? 0 : dd * N_NODES;
        hipMemsetAsync(Hf, 0, (size_t)rows * HIDDEN * 4, stream);
        for (int t = 0; t < LOOKBACK; ++t) {
            k_z1<<<(rows + 3) / 4, 256, 0, stream>>>(xa, W1, b1, (unsigned int*)Z1, rowOffset, rows, t);
            k_gemm_h2<<<(unsigned)nblk, 256, 0, stream>>>(Z1, W2T_bf, H2, rows);
            k_agg<<<(rows + 3) / 4, 256, 0, stream>>>((unsigned int*)H2, (unsigned int*)Z2, b2,
                                                      row_start, csr_src, csr_norm, self_norm, rowOffset, rows);
            k_grufused<<<(unsigned)nblk, 512, 0, stream>>>(Z2, Hf, Wih_bf, Whh_bf, b_fold, b_hh, rows);
        }
        k_out<<<(rows + 3) / 4, 256, 0, stream>>>(Hf, W_out, b_out, out, rowOffset, rows);
    }
}

// Round 7
// 1929.652 us; speedup vs baseline: 2.9426x; 1.2114x over previous
//
#include <hip/hip_runtime.h>
#include <cstddef>
#include <cstdint>

#define N_NODES 20000
#define N_EDGES 320000
#define NDAYS 4
#define LOOKBACK 7
#define NFEAT 5
#define XROW (LOOKBACK * NFEAT)  // 35
#define HIDDEN 128
#define TOTAL_ROWS (NDAYS * N_NODES)
#define CHUNK 5  // 16-row tiles per block in k_grufused; 80000/16/5 and 20000/16/5 are exact

typedef short bf8 __attribute__((ext_vector_type(8)));
typedef float fx4 __attribute__((ext_vector_type(4)));

__device__ __forceinline__ float bflo(unsigned int u) {
    union { unsigned int u; float f; } v; v.u = u << 16; return v.f;
}
__device__ __forceinline__ float bfhi(unsigned int u) {
    union { unsigned int u; float f; } v; v.u = u & 0xffff0000u; return v.f;
}
__device__ __forceinline__ unsigned short f2bf(float f) {
    union { float f; unsigned int u; } v; v.f = f;
    unsigned int u = v.u + 0x7fffu + ((v.u >> 16) & 1u);
    return (unsigned short)(u >> 16);
}
__device__ __forceinline__ unsigned int packbf(float a, float b) {
    return (unsigned int)f2bf(a) | ((unsigned int)f2bf(b) << 16);
}
__device__ __forceinline__ float sigm(float v) { return 1.0f / (1.0f + __expf(-v)); }
__device__ __forceinline__ float ftanh(float v) {
    float e2 = __expf(2.0f * v);
    return (e2 - 1.0f) / (e2 + 1.0f);
}

// ---------------- graph preprocessing ----------------

__global__ __launch_bounds__(256) void k_deg(const int* __restrict__ ei, int* __restrict__ deg) {
    int e = blockIdx.x * 256 + threadIdx.x;
    if (e < N_EDGES) atomicAdd(&deg[ei[N_EDGES + e]], 1);
}

__global__ __launch_bounds__(1024) void k_scan(const int* __restrict__ deg, int* __restrict__ row_start) {
    __shared__ int part[1024];
    int tid = threadIdx.x;
    const int chunk = (N_NODES + 1023) / 1024;  // 20
    int i0 = tid * chunk;
    int i1 = min(i0 + chunk, N_NODES);
    int s = 0;
    for (int i = i0; i < i1; ++i) s += deg[i];
    part[tid] = s;
    __syncthreads();
    for (int d = 1; d < 1024; d <<= 1) {
        int v = (tid >= d) ? part[tid - d] : 0;
        __syncthreads();
        part[tid] += v;
        __syncthreads();
    }
    int base = part[tid] - s;  // exclusive prefix
    for (int i = i0; i < i1; ++i) { row_start[i] = base; base += deg[i]; }
    if (tid == 1023) row_start[N_NODES] = part[1023];
}

__global__ __launch_bounds__(256) void k_dinv(const int* __restrict__ deg, float* __restrict__ dinv,
                                              float* __restrict__ self_norm) {
    int i = blockIdx.x * 256 + threadIdx.x;
    if (i >= N_NODES) return;
    float d = (float)(deg[i] + 1);
    dinv[i] = 1.0f / sqrtf(d);
    self_norm[i] = 1.0f / d;
}

__global__ __launch_bounds__(256) void k_fill(const int* __restrict__ ei, const int* __restrict__ row_start,
                                              int* __restrict__ cursor, const float* __restrict__ dinv,
                                              int* __restrict__ csr_src, float* __restrict__ csr_norm) {
    int e = blockIdx.x * 256 + threadIdx.x;
    if (e >= N_EDGES) return;
    int s = ei[e], d = ei[N_EDGES + e];
    int pos = row_start[d] + atomicAdd(&cursor[d], 1);
    csr_src[pos] = s;
    csr_norm[pos] = dinv[s] * dinv[d];
}

// W2T_bf[c][k] = bf16(W2[k][c])
__global__ __launch_bounds__(256) void k_w2t(const float* __restrict__ W2, unsigned short* __restrict__ W2T) {
    int idx = blockIdx.x * 256 + threadIdx.x;
    if (idx >= HIDDEN * HIDDEN) return;
    int k = idx >> 7, c = idx & 127;
    W2T[c * HIDDEN + k] = f2bf(W2[k * HIDDEN + c]);
}

__global__ __launch_bounds__(256) void k_cast(const float* __restrict__ src, unsigned short* __restrict__ dst, int n) {
    int i = blockIdx.x * 256 + threadIdx.x;
    if (i < n) dst[i] = f2bf(src[i]);
}

// b_fold[j] = b_ih[j] + b_hh[j] for r,z gates (j<256); b_ih[j] only for n gate
__global__ __launch_bounds__(256) void k_bfold(const float* __restrict__ b_ih, const float* __restrict__ b_hh,
                                               float* __restrict__ b_fold) {
    int i = blockIdx.x * 256 + threadIdx.x;
    if (i < 3 * HIDDEN) b_fold[i] = b_ih[i] + (i < 2 * HIDDEN ? b_hh[i] : 0.0f);
}

// ---------------- feature-space aggregation (once): xa = agg(x);  agg(x@W1) == agg(x)@W1 ----------------

__global__ __launch_bounds__(256) void k_aggx(const float* __restrict__ x, float* __restrict__ xa,
                                              const int* __restrict__ row_start, const int* __restrict__ csr_src,
                                              const float* __restrict__ csr_norm,
                                              const float* __restrict__ self_norm) {
    int g = blockIdx.x * 4 + (threadIdx.x >> 6);
    if (g >= TOTAL_ROWS) return;
    int lane = threadIdx.x & 63;
    if (lane >= XROW) return;
    int n = g % N_NODES;
    int dayBase = g - n;
    float acc = x[(size_t)g * XROW + lane] * self_norm[n];
    int e1 = row_start[n + 1];
    for (int e = row_start[n]; e < e1; ++e) {
        int s = csr_src[e];
        float w = csr_norm[e];
        acc += w * x[(size_t)(dayBase + s) * XROW + lane];
    }
    xa[(size_t)g * XROW + lane] = acc;
}

// ---------------- Z1 = relu(xa[:, t, :] @ W1 + b1)  (bf16 out) ----------------

__global__ __launch_bounds__(256) void k_z1(const float* __restrict__ xa, const float* __restrict__ W1,
                                            const float* __restrict__ b1,
                                            unsigned int* __restrict__ Z, int rowOffset, int nrows, int t) {
    int idx = blockIdx.x * 256 + threadIdx.x;
    int r = idx >> 6;
    if (r >= nrows) return;
    int lane = idx & 63;
    int c = lane * 2;
    const float* xp = xa + (size_t)(rowOffset + r) * XROW + t * NFEAT;
    float x0 = xp[0], x1 = xp[1], x2 = xp[2], x3 = xp[3], x4 = xp[4];
    float a0 = x0 * W1[c] + x1 * W1[128 + c] + x2 * W1[256 + c] + x3 * W1[384 + c] + x4 * W1[512 + c];
    float a1 = x0 * W1[c + 1] + x1 * W1[129 + c] + x2 * W1[257 + c] + x3 * W1[385 + c] + x4 * W1[513 + c];
    a0 = fmaxf(a0 + b1[c], 0.0f);
    a1 = fmaxf(a1 + b1[c + 1], 0.0f);
    Z[(size_t)r * 64 + lane] = packbf(a0, a1);
}

// ---------------- hidden-space aggregation (bf16 in/out): Z = relu(agg + self + b) ----------------

__global__ __launch_bounds__(256) void k_agg(const unsigned int* __restrict__ H, unsigned int* __restrict__ Z,
                                             const float* __restrict__ bias,
                                             const int* __restrict__ row_start, const int* __restrict__ csr_src,
                                             const float* __restrict__ csr_norm, const float* __restrict__ self_norm,
                                             int rowOffset, int nrows) {
    int r = blockIdx.x * 4 + (threadIdx.x >> 6);
    if (r >= nrows) return;
    int lane = threadIdx.x & 63;
    int g = rowOffset + r;
    int n = g % N_NODES;
    int dayLocalBase = (g - n) - rowOffset;
    unsigned int su = H[(size_t)r * 64 + lane];
    float sn = self_norm[n];
    float acc0 = bflo(su) * sn, acc1 = bfhi(su) * sn;
    int e1 = row_start[n + 1];
    for (int e = row_start[n]; e < e1; ++e) {
        int s = csr_src[e];
        float w = csr_norm[e];
        unsigned int hv = H[(size_t)(dayLocalBase + s) * 64 + lane];
        acc0 += w * bflo(hv);
        acc1 += w * bfhi(hv);
    }
    float2 b = ((const float2*)bias)[lane];
    acc0 = fmaxf(acc0 + b.x, 0.0f);
    acc1 = fmaxf(acc1 + b.y, 0.0f);
    Z[(size_t)r * 64 + lane] = packbf(acc0, acc1);
}

// ---------------- MFMA GEMM: H2 = Z1 @ W2  (out bf16 row-major) ----------------

__global__ __launch_bounds__(256) void k_gemm_h2(const unsigned short* __restrict__ A,
                                                 const unsigned short* __restrict__ W,
                                                 unsigned short* __restrict__ Out, int rows) {
    int tid = threadIdx.x, w = tid >> 6, l = tid & 63, lr = l & 15, lk = l >> 4;
    int rblk = blockIdx.x * 64;
    int rowA = rblk + w * 16 + lr;
    bool okA = rowA < rows;
    const bf8* Ap = (const bf8*)(A + (size_t)rowA * HIDDEN);
    const bf8* Bp = (const bf8*)W;
    fx4 acc[8];
#pragma unroll
    for (int n = 0; n < 8; ++n) acc[n] = (fx4){0.f, 0.f, 0.f, 0.f};
#pragma unroll
    for (int ks = 0; ks < 4; ++ks) {
        bf8 a = okA ? Ap[4 * ks + lk] : (bf8){0, 0, 0, 0, 0, 0, 0, 0};
#pragma unroll
        for (int n = 0; n < 8; ++n) {
            bf8 b = Bp[(size_t)(16 * n + lr) * 16 + 4 * ks + lk];
            acc[n] = __builtin_amdgcn_mfma_f32_16x16x32_bf16(a, b, acc[n], 0, 0, 0);
        }
    }
#pragma unroll
    for (int n = 0; n < 8; ++n)
#pragma unroll
        for (int r = 0; r < 4; ++r) {
            int row = rblk + w * 16 + lk * 4 + r;
            if (row < rows) Out[(size_t)row * HIDDEN + 16 * n + lr] = f2bf(acc[n][r]);
        }
}

// ---------------- fused GRU, B-stationary ----------------
// Wave w owns hidden cols [w*16, w*16+16) for all 3 gates x {W_ih, W_hh}: 24 B-fragments
// held in registers for the whole block. Block loops over CHUNK 16-row tiles:
// 8 A-loads (Z2 bf16 + Hbf bf16, double-buffered) -> 24 MFMA -> lane-local gate epilogue.
// One __syncthreads per tile fences the in-place Hbf read (all cols) vs write (own cols).

__global__ __launch_bounds__(512, 1) void k_grufused(const unsigned short* __restrict__ Z2,
                                                     float* __restrict__ Hf,
                                                     unsigned short* __restrict__ Hbf,
                                                     const unsigned short* __restrict__ Wih,
                                                     const unsigned short* __restrict__ Whh,
                                                     const float* __restrict__ bfold,
                                                     const float* __restrict__ bhh) {
    int tid = threadIdx.x, w = tid >> 6, l = tid & 63, lr = l & 15, lk = l >> 4;
    int tile0 = blockIdx.x * CHUNK;
    int c = w * 16 + lr;  // this lane's hidden column

    // persistent B fragments
    bf8 Bi[3][4], Bh[3][4];
    const bf8* BiP = (const bf8*)Wih;
    const bf8* BhP = (const bf8*)Whh;
#pragma unroll
    for (int g = 0; g < 3; ++g)
#pragma unroll
        for (int ks = 0; ks < 4; ++ks) {
            int rw = g * HIDDEN + c;  // weight row = output gate-col
            Bi[g][ks] = BiP[(size_t)rw * 16 + 4 * ks + lk];
            Bh[g][ks] = BhP[(size_t)rw * 16 + 4 * ks + lk];
        }

    const bf8* Az = (const bf8*)(Z2 + (size_t)(tile0 * 16 + lr) * HIDDEN);
    const bf8* Ah = (const bf8*)(Hbf + (size_t)(tile0 * 16 + lr) * HIDDEN);
    // per-tile advance in bf8 units: 16 rows * 128 cols / 8 = 256

    bf8 az[2][4], ah[2][4];
#pragma unroll
    for (int ks = 0; ks < 4; ++ks) {
        az[0][ks] = Az[4 * ks + lk];
        ah[0][ks] = Ah[4 * ks + lk];
    }

    float bf_r = bfold[c], bf_z = bfold[HIDDEN + c], bf_n = bfold[2 * HIDDEN + c];
    float bh_n = bhh[2 * HIDDEN + c];

#pragma unroll
    for (int mm = 0; mm < CHUNK; ++mm) {
        // all waves' A(mm) loads complete (vmcnt drain before barrier) -> safe to write rows(mm) below
        __syncthreads();
        const int cur = mm & 1, nxt = cur ^ 1;
        if (mm + 1 < CHUNK) {
#pragma unroll
            for (int ks = 0; ks < 4; ++ks) {
                az[nxt][ks] = Az[(mm + 1) * 256 + 4 * ks + lk];
                ah[nxt][ks] = Ah[(mm + 1) * 256 + 4 * ks + lk];
            }
        }
        fx4 ai[3], ag[3];
#pragma unroll
        for (int g = 0; g < 3; ++g) { ai[g] = (fx4){0.f, 0.f, 0.f, 0.f}; ag[g] = (fx4){0.f, 0.f, 0.f, 0.f}; }
#pragma unroll
        for (int ks = 0; ks < 4; ++ks)
#pragma unroll
            for (int g = 0; g < 3; ++g) {
                ai[g] = __builtin_amdgcn_mfma_f32_16x16x32_bf16(az[cur][ks], Bi[g][ks], ai[g], 0, 0, 0);
                ag[g] = __builtin_amdgcn_mfma_f32_16x16x32_bf16(ah[cur][ks], Bh[g][ks], ag[g], 0, 0, 0);
            }
        int rowb = (tile0 + mm) * 16 + lk * 4;
#pragma unroll
        for (int r = 0; r < 4; ++r) {
            size_t hidx = (size_t)(rowb + r) * HIDDEN + c;
            float hold = Hf[hidx];
            float rr = sigm(ai[0][r] + bf_r + ag[0][r]);
            float zz = sigm(ai[1][r] + bf_z + ag[1][r]);
            float nn = ftanh(ai[2][r] + bf_n + rr * (ag[2][r] + bh_n));
            float hnew = (1.0f - zz) * nn + zz * hold;
            Hf[hidx] = hnew;
            Hbf[hidx] = f2bf(hnew);
        }
    }
}

// ---------------- output head: softmax(h @ W_out + b_out) ----------------

__global__ __launch_bounds__(256) void k_out(const float* __restrict__ Hc, const float* __restrict__ Wo,
                                             const float* __restrict__ bo, float* __restrict__ out,
                                             int rowOffset, int nrows) {
    int r = blockIdx.x * 4 + (threadIdx.x >> 6);
    if (r >= nrows) return;
    int lane = threadIdx.x & 63;
    float2 hv = ((const float2*)(Hc + (size_t)r * HIDDEN))[lane];
    float l[5];
#pragma unroll
    for (int j = 0; j < 5; ++j) {
        float p = hv.x * Wo[(2 * lane) * 5 + j] + hv.y * Wo[(2 * lane + 1) * 5 + j];
#pragma unroll
        for (int s = 1; s < 64; s <<= 1) p += __shfl_xor(p, s);
        l[j] = p + bo[j];
    }
    float m = fmaxf(fmaxf(fmaxf(l[0], l[1]), fmaxf(l[2], l[3])), l[4]);
    float e0 = expf(l[0] - m), e1 = expf(l[1] - m), e2 = expf(l[2] - m), e3 = expf(l[3] - m), e4 = expf(l[4] - m);
    float inv = 1.0f / (e0 + e1 + e2 + e3 + e4);
    if (lane < 5) {
        float ej = lane == 0 ? e0 : lane == 1 ? e1 : lane == 2 ? e2 : lane == 3 ? e3 : e4;
        out[(size_t)(rowOffset + r) * 5 + lane] = ej * inv;
    }
}

// ---------------- launch ----------------

extern "C" void kernel_launch(void* const* d_in, const int* in_sizes, int n_in,
                              void* d_out, int out_size, void* d_ws, size_t ws_size,
                              hipStream_t stream) {
    const float* x     = (const float*)d_in[0];
    const int*   ei    = (const int*)d_in[1];
    const float* W1    = (const float*)d_in[2];
    const float* b1    = (const float*)d_in[3];
    const float* W2    = (const float*)d_in[4];
    const float* b2    = (const float*)d_in[5];
    const float* W_ih  = (const float*)d_in[6];
    const float* W_hh  = (const float*)d_in[7];
    const float* b_ih  = (const float*)d_in[8];
    const float* b_hh  = (const float*)d_in[9];
    const float* W_out = (const float*)d_in[10];
    const float* b_out = (const float*)d_in[11];
    float* out = (float*)d_out;

    size_t off = 0;
    char* wsb = (char*)d_ws;
    auto alloc = [&](size_t bytes) -> void* {
        void* p = wsb + off;
        off = (off + bytes + 255) & ~(size_t)255;
        return p;
    };
    int*            deg       = (int*)alloc(N_NODES * 4);
    int*            cursor    = (int*)alloc(N_NODES * 4);
    int*            row_start = (int*)alloc((N_NODES + 1) * 4);
    float*          dinv      = (float*)alloc(N_NODES * 4);
    float*          self_norm = (float*)alloc(N_NODES * 4);
    unsigned short* W2T_bf    = (unsigned short*)alloc(HIDDEN * HIDDEN * 2);
    unsigned short* Wih_bf    = (unsigned short*)alloc(3 * HIDDEN * HIDDEN * 2);
    unsigned short* Whh_bf    = (unsigned short*)alloc(3 * HIDDEN * HIDDEN * 2);
    float*          b_fold    = (float*)alloc(3 * HIDDEN * 4);
    int*            csr_src   = (int*)alloc(N_EDGES * 4);
    float*          csr_norm  = (float*)alloc(N_EDGES * 4);
    float*          xa        = (float*)alloc((size_t)TOTAL_ROWS * XROW * 4);  // 11.2 MB

    // per-row bytes: Z1 (256) + H2 (256) + Z2 (256) + Hf f32 (512) + Hbf (256) = 1536
    size_t prep_off = off;
    auto need = [&](int rows) -> size_t { return prep_off + (size_t)rows * 1536 + 4096; };
    bool batched = need(TOTAL_ROWS) <= ws_size;
    int rows = batched ? TOTAL_ROWS : N_NODES;
    size_t nblk = (size_t)(rows + 63) / 64;
    size_t actB = (size_t)rows * HIDDEN * 2;

    unsigned short* Z1  = (unsigned short*)alloc(actB);
    unsigned short* H2  = (unsigned short*)alloc(actB);
    unsigned short* Z2  = (unsigned short*)alloc(actB);
    float*          Hf  = (float*)alloc((size_t)rows * HIDDEN * 4);
    unsigned short* Hbf = (unsigned short*)alloc(actB);

    // graph + weight prep
    hipMemsetAsync(deg, 0, N_NODES * 4, stream);
    hipMemsetAsync(cursor, 0, N_NODES * 4, stream);
    k_deg<<<(N_EDGES + 255) / 256, 256, 0, stream>>>(ei, deg);
    k_scan<<<1, 1024, 0, stream>>>(deg, row_start);
    k_dinv<<<(N_NODES + 255) / 256, 256, 0, stream>>>(deg, dinv, self_norm);
    k_fill<<<(N_EDGES + 255) / 256, 256, 0, stream>>>(ei, row_start, cursor, dinv, csr_src, csr_norm);
    k_w2t<<<(HIDDEN * HIDDEN + 255) / 256, 256, 0, stream>>>(W2, W2T_bf);
    k_cast<<<(3 * HIDDEN * HIDDEN + 255) / 256, 256, 0, stream>>>(W_ih, Wih_bf, 3 * HIDDEN * HIDDEN);
    k_cast<<<(3 * HIDDEN * HIDDEN + 255) / 256, 256, 0, stream>>>(W_hh, Whh_bf, 3 * HIDDEN * HIDDEN);
    k_bfold<<<2, 256, 0, stream>>>(b_ih, b_hh, b_fold);
    k_aggx<<<(TOTAL_ROWS + 3) / 4, 256, 0, stream>>>(x, xa, row_start, csr_src, csr_norm, self_norm);

    int rounds = batched ? 1 : NDAYS;
    unsigned gru_grid = (unsigned)(rows / 16 / CHUNK);  // exact: 80000/80=1000, 20000/80=250
    for (int dd = 0; dd < rounds; ++dd) {
        int rowOffset = batched ? 0 : dd * N_NODES;
        hipMemsetAsync(Hf, 0, (size_t)rows * HIDDEN * 4, stream);
        hipMemsetAsync(Hbf, 0, actB, stream);
        for (int t = 0; t < LOOKBACK; ++t) {
            k_z1<<<(rows + 3) / 4, 256, 0, stream>>>(xa, W1, b1, (unsigned int*)Z1, rowOffset, rows, t);
            k_gemm_h2<<<(unsigned)nblk, 256, 0, stream>>>(Z1, W2T_bf, H2, rows);
            k_agg<<<(rows + 3) / 4, 256, 0, stream>>>((unsigned int*)H2, (unsigned int*)Z2, b2,
                                                      row_start, csr_src, csr_norm, self_norm, rowOffset, rows);
            k_grufused<<<gru_grid, 512, 0, stream>>>(Z2, Hf, Hbf, Wih_bf, Whh_bf, b_fold, b_hh);
        }
        k_out<<<(rows + 3) / 4, 256, 0, stream>>>(Hf, W_out, b_out, out, rowOffset, rows);
    }
}

// Round 8
// 1385.776 us; speedup vs baseline: 4.0975x; 1.3925x over previous
//
#include <hip/hip_runtime.h>
#include <cstddef>
#include <cstdint>

#define N_NODES 20000
#define N_EDGES 320000
#define NDAYS 4
#define LOOKBACK 7
#define NFEAT 5
#define XROW (LOOKBACK * NFEAT)  // 35
#define HIDDEN 128
#define TOTAL_ROWS (NDAYS * N_NODES)
#define CHUNK 5  // 16-row tiles per block in k_grufused; 80000/80 and 20000/80 exact

typedef short bf8 __attribute__((ext_vector_type(8)));
typedef float fx4 __attribute__((ext_vector_type(4)));

__device__ __forceinline__ float bflo(unsigned int u) {
    union { unsigned int u; float f; } v; v.u = u << 16; return v.f;
}
__device__ __forceinline__ float bfhi(unsigned int u) {
    union { unsigned int u; float f; } v; v.u = u & 0xffff0000u; return v.f;
}
__device__ __forceinline__ unsigned short f2bf(float f) {
    union { float f; unsigned int u; } v; v.f = f;
    unsigned int u = v.u + 0x7fffu + ((v.u >> 16) & 1u);
    return (unsigned short)(u >> 16);
}
__device__ __forceinline__ unsigned int packbf(float a, float b) {
    return (unsigned int)f2bf(a) | ((unsigned int)f2bf(b) << 16);
}
__device__ __forceinline__ float sigm(float v) { return 1.0f / (1.0f + __expf(-v)); }
__device__ __forceinline__ float ftanh(float v) {
    float e2 = __expf(2.0f * v);
    return (e2 - 1.0f) / (e2 + 1.0f);
}
__device__ __forceinline__ void accum8(float* a, uint4 v, float w) {
    a[0] += w * bflo(v.x); a[1] += w * bfhi(v.x);
    a[2] += w * bflo(v.y); a[3] += w * bfhi(v.y);
    a[4] += w * bflo(v.z); a[5] += w * bfhi(v.z);
    a[6] += w * bflo(v.w); a[7] += w * bfhi(v.w);
}

// ---------------- graph preprocessing ----------------

__global__ __launch_bounds__(256) void k_deg(const int* __restrict__ ei, int* __restrict__ deg) {
    int e = blockIdx.x * 256 + threadIdx.x;
    if (e < N_EDGES) atomicAdd(&deg[ei[N_EDGES + e]], 1);
}

__global__ __launch_bounds__(1024) void k_scan(const int* __restrict__ deg, int* __restrict__ row_start) {
    __shared__ int part[1024];
    int tid = threadIdx.x;
    const int chunk = (N_NODES + 1023) / 1024;  // 20
    int i0 = tid * chunk;
    int i1 = min(i0 + chunk, N_NODES);
    int s = 0;
    for (int i = i0; i < i1; ++i) s += deg[i];
    part[tid] = s;
    __syncthreads();
    for (int d = 1; d < 1024; d <<= 1) {
        int v = (tid >= d) ? part[tid - d] : 0;
        __syncthreads();
        part[tid] += v;
        __syncthreads();
    }
    int base = part[tid] - s;  // exclusive prefix
    for (int i = i0; i < i1; ++i) { row_start[i] = base; base += deg[i]; }
    if (tid == 1023) row_start[N_NODES] = part[1023];
}

__global__ __launch_bounds__(256) void k_dinv(const int* __restrict__ deg, float* __restrict__ dinv,
                                              float* __restrict__ self_norm) {
    int i = blockIdx.x * 256 + threadIdx.x;
    if (i >= N_NODES) return;
    float d = (float)(deg[i] + 1);
    dinv[i] = 1.0f / sqrtf(d);
    self_norm[i] = 1.0f / d;
}

__global__ __launch_bounds__(256) void k_fill(const int* __restrict__ ei, const int* __restrict__ row_start,
                                              int* __restrict__ cursor, const float* __restrict__ dinv,
                                              int* __restrict__ csr_src, float* __restrict__ csr_norm) {
    int e = blockIdx.x * 256 + threadIdx.x;
    if (e >= N_EDGES) return;
    int s = ei[e], d = ei[N_EDGES + e];
    int pos = row_start[d] + atomicAdd(&cursor[d], 1);
    csr_src[pos] = s;
    csr_norm[pos] = dinv[s] * dinv[d];
}

// W2T_bf[c][k] = bf16(W2[k][c])
__global__ __launch_bounds__(256) void k_w2t(const float* __restrict__ W2, unsigned short* __restrict__ W2T) {
    int idx = blockIdx.x * 256 + threadIdx.x;
    if (idx >= HIDDEN * HIDDEN) return;
    int k = idx >> 7, c = idx & 127;
    W2T[c * HIDDEN + k] = f2bf(W2[k * HIDDEN + c]);
}

__global__ __launch_bounds__(256) void k_cast(const float* __restrict__ src, unsigned short* __restrict__ dst, int n) {
    int i = blockIdx.x * 256 + threadIdx.x;
    if (i < n) dst[i] = f2bf(src[i]);
}

// b_fold[j] = b_ih[j] + b_hh[j] for r,z gates (j<256); b_ih[j] only for n gate
__global__ __launch_bounds__(256) void k_bfold(const float* __restrict__ b_ih, const float* __restrict__ b_hh,
                                               float* __restrict__ b_fold) {
    int i = blockIdx.x * 256 + threadIdx.x;
    if (i < 3 * HIDDEN) b_fold[i] = b_ih[i] + (i < 2 * HIDDEN ? b_hh[i] : 0.0f);
}

// ---------------- feature-space aggregation: xa[node*NB+b] = agg(x)[day b] ----------------
// agg(x@W1) == agg(x)@W1; one wave per node, NB-day ILP per edge.

template<int NB>
__global__ __launch_bounds__(256) void k_aggx(const float* __restrict__ x, float* __restrict__ xa,
                                              const int* __restrict__ row_start, const int* __restrict__ csr_src,
                                              const float* __restrict__ csr_norm,
                                              const float* __restrict__ self_norm, int dayBase) {
    int n = blockIdx.x * 4 + (threadIdx.x >> 6);
    if (n >= N_NODES) return;
    int lane = threadIdx.x & 63;
    if (lane >= XROW) return;
    float sn = self_norm[n];
    float acc[NB];
#pragma unroll
    for (int b = 0; b < NB; ++b)
        acc[b] = x[(size_t)((dayBase + b) * N_NODES + n) * XROW + lane] * sn;
    int e1 = row_start[n + 1];
    for (int e = row_start[n]; e < e1; ++e) {
        int s = csr_src[e];
        float w = csr_norm[e];
#pragma unroll
        for (int b = 0; b < NB; ++b)
            acc[b] += w * x[(size_t)((dayBase + b) * N_NODES + s) * XROW + lane];
    }
#pragma unroll
    for (int b = 0; b < NB; ++b)
        xa[(size_t)(n * NB + b) * XROW + lane] = acc[b];
}

// ---------------- Z1 = relu(xa[:, t, :] @ W1 + b1)  (bf16 out, row-wise on internal rows) ----------------

__global__ __launch_bounds__(256) void k_z1(const float* __restrict__ xa, const float* __restrict__ W1,
                                            const float* __restrict__ b1,
                                            unsigned int* __restrict__ Z, int nrows, int t) {
    int idx = blockIdx.x * 256 + threadIdx.x;
    int r = idx >> 6;
    if (r >= nrows) return;
    int lane = idx & 63;
    int c = lane * 2;
    const float* xp = xa + (size_t)r * XROW + t * NFEAT;
    float x0 = xp[0], x1 = xp[1], x2 = xp[2], x3 = xp[3], x4 = xp[4];
    float a0 = x0 * W1[c] + x1 * W1[128 + c] + x2 * W1[256 + c] + x3 * W1[384 + c] + x4 * W1[512 + c];
    float a1 = x0 * W1[c + 1] + x1 * W1[129 + c] + x2 * W1[257 + c] + x3 * W1[385 + c] + x4 * W1[513 + c];
    a0 = fmaxf(a0 + b1[c], 0.0f);
    a1 = fmaxf(a1 + b1[c + 1], 0.0f);
    Z[(size_t)r * 64 + lane] = packbf(a0, a1);
}

// ---------------- hidden-space aggregation, interleaved layout ----------------
// One wave per node. Lane l: day = l>>4, channels 8*(l&15)..+7. One uint4 (16B) per edge per lane
// = 1KB contiguous per wave covering all NB days. Edge loop unrolled x4.

template<int NB>
__global__ __launch_bounds__(256) void k_agg(const uint4* __restrict__ H, uint4* __restrict__ Z,
                                             const float* __restrict__ bias,
                                             const int* __restrict__ row_start, const int* __restrict__ csr_src,
                                             const float* __restrict__ csr_norm,
                                             const float* __restrict__ self_norm) {
    int n = blockIdx.x * 4 + (threadIdx.x >> 6);
    if (n >= N_NODES) return;
    int l = threadIdx.x & 63;
    if (l >= NB * 16) return;
    int c0 = (l & 15) * 8;
    float sn = self_norm[n];
    float a[8];
    {
        uint4 sv = H[(size_t)n * (NB * 16) + l];
        a[0] = bflo(sv.x) * sn; a[1] = bfhi(sv.x) * sn;
        a[2] = bflo(sv.y) * sn; a[3] = bfhi(sv.y) * sn;
        a[4] = bflo(sv.z) * sn; a[5] = bfhi(sv.z) * sn;
        a[6] = bflo(sv.w) * sn; a[7] = bfhi(sv.w) * sn;
    }
    int e1 = row_start[n + 1];
    int e = row_start[n];
    for (; e + 3 < e1; e += 4) {
        int s0 = csr_src[e], s1 = csr_src[e + 1], s2 = csr_src[e + 2], s3 = csr_src[e + 3];
        float w0 = csr_norm[e], w1 = csr_norm[e + 1], w2 = csr_norm[e + 2], w3 = csr_norm[e + 3];
        uint4 v0 = H[(size_t)s0 * (NB * 16) + l];
        uint4 v1 = H[(size_t)s1 * (NB * 16) + l];
        uint4 v2 = H[(size_t)s2 * (NB * 16) + l];
        uint4 v3 = H[(size_t)s3 * (NB * 16) + l];
        accum8(a, v0, w0); accum8(a, v1, w1); accum8(a, v2, w2); accum8(a, v3, w3);
    }
    for (; e < e1; ++e) {
        int s = csr_src[e];
        float w = csr_norm[e];
        uint4 v = H[(size_t)s * (NB * 16) + l];
        accum8(a, v, w);
    }
    const float* bp = bias + c0;
    uint4 o;
    o.x = packbf(fmaxf(a[0] + bp[0], 0.f), fmaxf(a[1] + bp[1], 0.f));
    o.y = packbf(fmaxf(a[2] + bp[2], 0.f), fmaxf(a[3] + bp[3], 0.f));
    o.z = packbf(fmaxf(a[4] + bp[4], 0.f), fmaxf(a[5] + bp[5], 0.f));
    o.w = packbf(fmaxf(a[6] + bp[6], 0.f), fmaxf(a[7] + bp[7], 0.f));
    Z[(size_t)n * (NB * 16) + l] = o;
}

// ---------------- MFMA GEMM: H2 = Z1 @ W2  (out bf16 row-major) ----------------

__global__ __launch_bounds__(256) void k_gemm_h2(const unsigned short* __restrict__ A,
                                                 const unsigned short* __restrict__ W,
                                                 unsigned short* __restrict__ Out, int rows) {
    int tid = threadIdx.x, w = tid >> 6, l = tid & 63, lr = l & 15, lk = l >> 4;
    int rblk = blockIdx.x * 64;
    int rowA = rblk + w * 16 + lr;
    bool okA = rowA < rows;
    const bf8* Ap = (const bf8*)(A + (size_t)rowA * HIDDEN);
    const bf8* Bp = (const bf8*)W;
    fx4 acc[8];
#pragma unroll
    for (int n = 0; n < 8; ++n) acc[n] = (fx4){0.f, 0.f, 0.f, 0.f};
#pragma unroll
    for (int ks = 0; ks < 4; ++ks) {
        bf8 a = okA ? Ap[4 * ks + lk] : (bf8){0, 0, 0, 0, 0, 0, 0, 0};
#pragma unroll
        for (int n = 0; n < 8; ++n) {
            bf8 b = Bp[(size_t)(16 * n + lr) * 16 + 4 * ks + lk];
            acc[n] = __builtin_amdgcn_mfma_f32_16x16x32_bf16(a, b, acc[n], 0, 0, 0);
        }
    }
#pragma unroll
    for (int n = 0; n < 8; ++n)
#pragma unroll
        for (int r = 0; r < 4; ++r) {
            int row = rblk + w * 16 + lk * 4 + r;
            if (row < rows) Out[(size_t)row * HIDDEN + 16 * n + lr] = f2bf(acc[n][r]);
        }
}

// ---------------- fused GRU, B-stationary (row-agnostic) ----------------

__global__ __launch_bounds__(512, 1) void k_grufused(const unsigned short* __restrict__ Z2,
                                                     float* __restrict__ Hf,
                                                     unsigned short* __restrict__ Hbf,
                                                     const unsigned short* __restrict__ Wih,
                                                     const unsigned short* __restrict__ Whh,
                                                     const float* __restrict__ bfold,
                                                     const float* __restrict__ bhh) {
    int tid = threadIdx.x, w = tid >> 6, l = tid & 63, lr = l & 15, lk = l >> 4;
    int tile0 = blockIdx.x * CHUNK;
    int c = w * 16 + lr;

    bf8 Bi[3][4], Bh[3][4];
    const bf8* BiP = (const bf8*)Wih;
    const bf8* BhP = (const bf8*)Whh;
#pragma unroll
    for (int g = 0; g < 3; ++g)
#pragma unroll
        for (int ks = 0; ks < 4; ++ks) {
            int rw = g * HIDDEN + c;
            Bi[g][ks] = BiP[(size_t)rw * 16 + 4 * ks + lk];
            Bh[g][ks] = BhP[(size_t)rw * 16 + 4 * ks + lk];
        }

    const bf8* Az = (const bf8*)(Z2 + (size_t)(tile0 * 16 + lr) * HIDDEN);
    const bf8* Ah = (const bf8*)(Hbf + (size_t)(tile0 * 16 + lr) * HIDDEN);

    bf8 az[2][4], ah[2][4];
#pragma unroll
    for (int ks = 0; ks < 4; ++ks) {
        az[0][ks] = Az[4 * ks + lk];
        ah[0][ks] = Ah[4 * ks + lk];
    }

    float bf_r = bfold[c], bf_z = bfold[HIDDEN + c], bf_n = bfold[2 * HIDDEN + c];
    float bh_n = bhh[2 * HIDDEN + c];

#pragma unroll
    for (int mm = 0; mm < CHUNK; ++mm) {
        __syncthreads();
        const int cur = mm & 1, nxt = cur ^ 1;
        if (mm + 1 < CHUNK) {
#pragma unroll
            for (int ks = 0; ks < 4; ++ks) {
                az[nxt][ks] = Az[(mm + 1) * 256 + 4 * ks + lk];
                ah[nxt][ks] = Ah[(mm + 1) * 256 + 4 * ks + lk];
            }
        }
        fx4 ai[3], ag[3];
#pragma unroll
        for (int g = 0; g < 3; ++g) { ai[g] = (fx4){0.f, 0.f, 0.f, 0.f}; ag[g] = (fx4){0.f, 0.f, 0.f, 0.f}; }
#pragma unroll
        for (int ks = 0; ks < 4; ++ks)
#pragma unroll
            for (int g = 0; g < 3; ++g) {
                ai[g] = __builtin_amdgcn_mfma_f32_16x16x32_bf16(az[cur][ks], Bi[g][ks], ai[g], 0, 0, 0);
                ag[g] = __builtin_amdgcn_mfma_f32_16x16x32_bf16(ah[cur][ks], Bh[g][ks], ag[g], 0, 0, 0);
            }
        int rowb = (tile0 + mm) * 16 + lk * 4;
#pragma unroll
        for (int r = 0; r < 4; ++r) {
            size_t hidx = (size_t)(rowb + r) * HIDDEN + c;
            float hold = Hf[hidx];
            float rr = sigm(ai[0][r] + bf_r + ag[0][r]);
            float zz = sigm(ai[1][r] + bf_z + ag[1][r]);
            float nn = ftanh(ai[2][r] + bf_n + rr * (ag[2][r] + bh_n));
            float hnew = (1.0f - zz) * nn + zz * hold;
            Hf[hidx] = hnew;
            Hbf[hidx] = f2bf(hnew);
        }
    }
}

// ---------------- output head: softmax(h @ W_out + b_out) ----------------

template<int NB>
__global__ __launch_bounds__(256) void k_out(const float* __restrict__ Hc, const float* __restrict__ Wo,
                                             const float* __restrict__ bo, float* __restrict__ out,
                                             int dayBase) {
    int rr = blockIdx.x * 4 + (threadIdx.x >> 6);
    if (rr >= N_NODES * NB) return;
    int lane = threadIdx.x & 63;
    float2 hv = ((const float2*)(Hc + (size_t)rr * HIDDEN))[lane];
    float l[5];
#pragma unroll
    for (int j = 0; j < 5; ++j) {
        float p = hv.x * Wo[(2 * lane) * 5 + j] + hv.y * Wo[(2 * lane + 1) * 5 + j];
#pragma unroll
        for (int s = 1; s < 64; s <<= 1) p += __shfl_xor(p, s);
        l[j] = p + bo[j];
    }
    float m = fmaxf(fmaxf(fmaxf(l[0], l[1]), fmaxf(l[2], l[3])), l[4]);
    float e0 = expf(l[0] - m), e1 = expf(l[1] - m), e2 = expf(l[2] - m), e3 = expf(l[3] - m), e4 = expf(l[4] - m);
    float inv = 1.0f / (e0 + e1 + e2 + e3 + e4);
    if (lane < 5) {
        float ej = lane == 0 ? e0 : lane == 1 ? e1 : lane == 2 ? e2 : lane == 3 ? e3 : e4;
        int n = rr / NB, dd = dayBase + rr % NB;
        out[((size_t)dd * N_NODES + n) * 5 + lane] = ej * inv;
    }
}

// ---------------- launch ----------------

extern "C" void kernel_launch(void* const* d_in, const int* in_sizes, int n_in,
                              void* d_out, int out_size, void* d_ws, size_t ws_size,
                              hipStream_t stream) {
    const float* x     = (const float*)d_in[0];
    const int*   ei    = (const int*)d_in[1];
    const float* W1    = (const float*)d_in[2];
    const float* b1    = (const float*)d_in[3];
    const float* W2    = (const float*)d_in[4];
    const float* b2    = (const float*)d_in[5];
    const float* W_ih  = (const float*)d_in[6];
    const float* W_hh  = (const float*)d_in[7];
    const float* b_ih  = (const float*)d_in[8];
    const float* b_hh  = (const float*)d_in[9];
    const float* W_out = (const float*)d_in[10];
    const float* b_out = (const float*)d_in[11];
    float* out = (float*)d_out;

    size_t off = 0;
    char* wsb = (char*)d_ws;
    auto alloc = [&](size_t bytes) -> void* {
        void* p = wsb + off;
        off = (off + bytes + 255) & ~(size_t)255;
        return p;
    };
    int*            deg       = (int*)alloc(N_NODES * 4);
    int*            cursor    = (int*)alloc(N_NODES * 4);
    int*            row_start = (int*)alloc((N_NODES + 1) * 4);
    float*          dinv      = (float*)alloc(N_NODES * 4);
    float*          self_norm = (float*)alloc(N_NODES * 4);
    unsigned short* W2T_bf    = (unsigned short*)alloc(HIDDEN * HIDDEN * 2);
    unsigned short* Wih_bf    = (unsigned short*)alloc(3 * HIDDEN * HIDDEN * 2);
    unsigned short* Whh_bf    = (unsigned short*)alloc(3 * HIDDEN * HIDDEN * 2);
    float*          b_fold    = (float*)alloc(3 * HIDDEN * 4);
    int*            csr_src   = (int*)alloc(N_EDGES * 4);
    float*          csr_norm  = (float*)alloc(N_EDGES * 4);

    // per-row bytes: xa (140) + Z1 (256) + H2 (256) + Z2 (256) + Hf f32 (512) + Hbf (256)
    size_t prep_off = off;
    auto need = [&](int rows) -> size_t { return prep_off + (size_t)rows * (140 + 4 + 1536) + 8192; };
    bool batched = need(TOTAL_ROWS) <= ws_size;
    int rows = batched ? TOTAL_ROWS : N_NODES;
    size_t nblk = (size_t)(rows + 63) / 64;
    size_t actB = (size_t)rows * HIDDEN * 2;

    float*          xa  = (float*)alloc((size_t)rows * XROW * 4);
    unsigned short* Z1  = (unsigned short*)alloc(actB);
    unsigned short* H2  = (unsigned short*)alloc(actB);
    unsigned short* Z2  = (unsigned short*)alloc(actB);
    float*          Hf  = (float*)alloc((size_t)rows * HIDDEN * 4);
    unsigned short* Hbf = (unsigned short*)alloc(actB);

    // graph + weight prep
    hipMemsetAsync(deg, 0, N_NODES * 4, stream);
    hipMemsetAsync(cursor, 0, N_NODES * 4, stream);
    k_deg<<<(N_EDGES + 255) / 256, 256, 0, stream>>>(ei, deg);
    k_scan<<<1, 1024, 0, stream>>>(deg, row_start);
    k_dinv<<<(N_NODES + 255) / 256, 256, 0, stream>>>(deg, dinv, self_norm);
    k_fill<<<(N_EDGES + 255) / 256, 256, 0, stream>>>(ei, row_start, cursor, dinv, csr_src, csr_norm);
    k_w2t<<<(HIDDEN * HIDDEN + 255) / 256, 256, 0, stream>>>(W2, W2T_bf);
    k_cast<<<(3 * HIDDEN * HIDDEN + 255) / 256, 256, 0, stream>>>(W_ih, Wih_bf, 3 * HIDDEN * HIDDEN);
    k_cast<<<(3 * HIDDEN * HIDDEN + 255) / 256, 256, 0, stream>>>(W_hh, Whh_bf, 3 * HIDDEN * HIDDEN);
    k_bfold<<<2, 256, 0, stream>>>(b_ih, b_hh, b_fold);

    unsigned ngrid = (N_NODES + 3) / 4;
    unsigned gru_grid = (unsigned)(rows / 16 / CHUNK);  // 1000 or 250, exact
    int rounds = batched ? 1 : NDAYS;
    for (int dd = 0; dd < rounds; ++dd) {
        int dayBase = batched ? 0 : dd;
        if (batched)
            k_aggx<NDAYS><<<ngrid, 256, 0, stream>>>(x, xa, row_start, csr_src, csr_norm, self_norm, 0);
        else
            k_aggx<1><<<ngrid, 256, 0, stream>>>(x, xa, row_start, csr_src, csr_norm, self_norm, dayBase);
        hipMemsetAsync(Hf, 0, (size_t)rows * HIDDEN * 4, stream);
        hipMemsetAsync(Hbf, 0, actB, stream);
        for (int t = 0; t < LOOKBACK; ++t) {
            k_z1<<<(rows + 3) / 4, 256, 0, stream>>>(xa, W1, b1, (unsigned int*)Z1, rows, t);
            k_gemm_h2<<<(unsigned)nblk, 256, 0, stream>>>(Z1, W2T_bf, H2, rows);
            if (batched)
                k_agg<NDAYS><<<ngrid, 256, 0, stream>>>((const uint4*)H2, (uint4*)Z2, b2,
                                                        row_start, csr_src, csr_norm, self_norm);
            else
                k_agg<1><<<ngrid, 256, 0, stream>>>((const uint4*)H2, (uint4*)Z2, b2,
                                                    row_start, csr_src, csr_norm, self_norm);
            k_grufused<<<gru_grid, 512, 0, stream>>>(Z2, Hf, Hbf, Wih_bf, Whh_bf, b_fold, b_hh);
        }
        if (batched)
            k_out<NDAYS><<<(rows + 3) / 4, 256, 0, stream>>>(Hf, W_out, b_out, out, 0);
        else
            k_out<1><<<(rows + 3) / 4, 256, 0, stream>>>(Hf, W_out, b_out, out, dayBase);
    }
}

// Round 9
// 1016.743 us; speedup vs baseline: 5.5847x; 1.3630x over previous
//
#include <hip/hip_runtime.h>
#include <cstddef>
#include <cstdint>

#define N_NODES 20000
#define N_EDGES 320000
#define NDAYS 4
#define LOOKBACK 7
#define NFEAT 5
#define XROW (LOOKBACK * NFEAT)  // 35
#define HIDDEN 128
#define GRUROWS 80  // rows per k_megagru block; 20000*NB % 80 == 0 for NB in {1,2,4}

typedef short bf8 __attribute__((ext_vector_type(8)));
typedef float fx4 __attribute__((ext_vector_type(4)));

__device__ __forceinline__ float bflo(unsigned int u) {
    union { unsigned int u; float f; } v; v.u = u << 16; return v.f;
}
__device__ __forceinline__ float bfhi(unsigned int u) {
    union { unsigned int u; float f; } v; v.u = u & 0xffff0000u; return v.f;
}
__device__ __forceinline__ unsigned short f2bf(float f) {
    union { float f; unsigned int u; } v; v.f = f;
    unsigned int u = v.u + 0x7fffu + ((v.u >> 16) & 1u);
    return (unsigned short)(u >> 16);
}
__device__ __forceinline__ unsigned int packbf(float a, float b) {
    return (unsigned int)f2bf(a) | ((unsigned int)f2bf(b) << 16);
}
__device__ __forceinline__ float sigm(float v) { return 1.0f / (1.0f + __expf(-v)); }
__device__ __forceinline__ float ftanh(float v) {
    float e2 = __expf(2.0f * v);
    return (e2 - 1.0f) / (e2 + 1.0f);
}
__device__ __forceinline__ void accum8(float* a, uint4 v, float w) {
    a[0] += w * bflo(v.x); a[1] += w * bfhi(v.x);
    a[2] += w * bflo(v.y); a[3] += w * bfhi(v.y);
    a[4] += w * bflo(v.z); a[5] += w * bfhi(v.z);
    a[6] += w * bflo(v.w); a[7] += w * bfhi(v.w);
}

// ---------------- graph preprocessing ----------------

__global__ __launch_bounds__(256) void k_deg(const int* __restrict__ ei, int* __restrict__ deg) {
    int e = blockIdx.x * 256 + threadIdx.x;
    if (e < N_EDGES) atomicAdd(&deg[ei[N_EDGES + e]], 1);
}

__global__ __launch_bounds__(1024) void k_scan(const int* __restrict__ deg, int* __restrict__ row_start) {
    __shared__ int part[1024];
    int tid = threadIdx.x;
    const int chunk = (N_NODES + 1023) / 1024;  // 20
    int i0 = tid * chunk;
    int i1 = min(i0 + chunk, N_NODES);
    int s = 0;
    for (int i = i0; i < i1; ++i) s += deg[i];
    part[tid] = s;
    __syncthreads();
    for (int d = 1; d < 1024; d <<= 1) {
        int v = (tid >= d) ? part[tid - d] : 0;
        __syncthreads();
        part[tid] += v;
        __syncthreads();
    }
    int base = part[tid] - s;  // exclusive prefix
    for (int i = i0; i < i1; ++i) { row_start[i] = base; base += deg[i]; }
    if (tid == 1023) row_start[N_NODES] = part[1023];
}

__global__ __launch_bounds__(256) void k_dinv(const int* __restrict__ deg, float* __restrict__ dinv,
                                              float* __restrict__ self_norm) {
    int i = blockIdx.x * 256 + threadIdx.x;
    if (i >= N_NODES) return;
    float d = (float)(deg[i] + 1);
    dinv[i] = 1.0f / sqrtf(d);
    self_norm[i] = 1.0f / d;
}

__global__ __launch_bounds__(256) void k_fill(const int* __restrict__ ei, const int* __restrict__ row_start,
                                              int* __restrict__ cursor, const float* __restrict__ dinv,
                                              int* __restrict__ csr_src, float* __restrict__ csr_norm) {
    int e = blockIdx.x * 256 + threadIdx.x;
    if (e >= N_EDGES) return;
    int s = ei[e], d = ei[N_EDGES + e];
    int pos = row_start[d] + atomicAdd(&cursor[d], 1);
    csr_src[pos] = s;
    csr_norm[pos] = dinv[s] * dinv[d];
}

// W2T_bf[c][k] = bf16(W2[k][c])
__global__ __launch_bounds__(256) void k_w2t(const float* __restrict__ W2, unsigned short* __restrict__ W2T) {
    int idx = blockIdx.x * 256 + threadIdx.x;
    if (idx >= HIDDEN * HIDDEN) return;
    int k = idx >> 7, c = idx & 127;
    W2T[c * HIDDEN + k] = f2bf(W2[k * HIDDEN + c]);
}

__global__ __launch_bounds__(256) void k_cast(const float* __restrict__ src, unsigned short* __restrict__ dst, int n) {
    int i = blockIdx.x * 256 + threadIdx.x;
    if (i < n) dst[i] = f2bf(src[i]);
}

// b_fold[j] = b_ih[j] + b_hh[j] for r,z gates (j<256); b_ih[j] only for n gate
__global__ __launch_bounds__(256) void k_bfold(const float* __restrict__ b_ih, const float* __restrict__ b_hh,
                                               float* __restrict__ b_fold) {
    int i = blockIdx.x * 256 + threadIdx.x;
    if (i < 3 * HIDDEN) b_fold[i] = b_ih[i] + (i < 2 * HIDDEN ? b_hh[i] : 0.0f);
}

// ---------------- feature-space aggregation: xa[node*NB+b] = agg(x)[day b] ----------------

template<int NB>
__global__ __launch_bounds__(256) void k_aggx(const float* __restrict__ x, float* __restrict__ xa,
                                              const int* __restrict__ row_start, const int* __restrict__ csr_src,
                                              const float* __restrict__ csr_norm,
                                              const float* __restrict__ self_norm, int dayBase) {
    int n = blockIdx.x * 4 + (threadIdx.x >> 6);
    if (n >= N_NODES) return;
    int lane = threadIdx.x & 63;
    if (lane >= XROW) return;
    float sn = self_norm[n];
    float acc[NB];
#pragma unroll
    for (int b = 0; b < NB; ++b)
        acc[b] = x[(size_t)((dayBase + b) * N_NODES + n) * XROW + lane] * sn;
    int e1 = row_start[n + 1];
    for (int e = row_start[n]; e < e1; ++e) {
        int s = csr_src[e];
        float w = csr_norm[e];
#pragma unroll
        for (int b = 0; b < NB; ++b)
            acc[b] += w * x[(size_t)((dayBase + b) * N_NODES + s) * XROW + lane];
    }
#pragma unroll
    for (int b = 0; b < NB; ++b)
        xa[(size_t)(n * NB + b) * XROW + lane] = acc[b];
}

// ---------------- Z1 = relu(xa[:, t, :] @ W1 + b1)  (bf16 out) ----------------

__global__ __launch_bounds__(256) void k_z1(const float* __restrict__ xa, const float* __restrict__ W1,
                                            const float* __restrict__ b1,
                                            unsigned int* __restrict__ Z, int nrows, int t) {
    int idx = blockIdx.x * 256 + threadIdx.x;
    int r = idx >> 6;
    if (r >= nrows) return;
    int lane = idx & 63;
    int c = lane * 2;
    const float* xp = xa + (size_t)r * XROW + t * NFEAT;
    float x0 = xp[0], x1 = xp[1], x2 = xp[2], x3 = xp[3], x4 = xp[4];
    float a0 = x0 * W1[c] + x1 * W1[128 + c] + x2 * W1[256 + c] + x3 * W1[384 + c] + x4 * W1[512 + c];
    float a1 = x0 * W1[c + 1] + x1 * W1[129 + c] + x2 * W1[257 + c] + x3 * W1[385 + c] + x4 * W1[513 + c];
    a0 = fmaxf(a0 + b1[c], 0.0f);
    a1 = fmaxf(a1 + b1[c + 1], 0.0f);
    Z[(size_t)r * 64 + lane] = packbf(a0, a1);
}

// ---------------- hidden-space aggregation, day-interleaved layout ----------------

template<int NB>
__global__ __launch_bounds__(256) void k_agg(const uint4* __restrict__ H, uint4* __restrict__ Z,
                                             const float* __restrict__ bias,
                                             const int* __restrict__ row_start, const int* __restrict__ csr_src,
                                             const float* __restrict__ csr_norm,
                                             const float* __restrict__ self_norm) {
    int n = blockIdx.x * 4 + (threadIdx.x >> 6);
    if (n >= N_NODES) return;
    int l = threadIdx.x & 63;
    if (l >= NB * 16) return;
    int c0 = (l & 15) * 8;
    float sn = self_norm[n];
    float a[8];
    {
        uint4 sv = H[(size_t)n * (NB * 16) + l];
        a[0] = bflo(sv.x) * sn; a[1] = bfhi(sv.x) * sn;
        a[2] = bflo(sv.y) * sn; a[3] = bfhi(sv.y) * sn;
        a[4] = bflo(sv.z) * sn; a[5] = bfhi(sv.z) * sn;
        a[6] = bflo(sv.w) * sn; a[7] = bfhi(sv.w) * sn;
    }
    int e1 = row_start[n + 1];
    int e = row_start[n];
    for (; e + 3 < e1; e += 4) {
        int s0 = csr_src[e], s1 = csr_src[e + 1], s2 = csr_src[e + 2], s3 = csr_src[e + 3];
        float w0 = csr_norm[e], w1 = csr_norm[e + 1], w2 = csr_norm[e + 2], w3 = csr_norm[e + 3];
        uint4 v0 = H[(size_t)s0 * (NB * 16) + l];
        uint4 v1 = H[(size_t)s1 * (NB * 16) + l];
        uint4 v2 = H[(size_t)s2 * (NB * 16) + l];
        uint4 v3 = H[(size_t)s3 * (NB * 16) + l];
        accum8(a, v0, w0); accum8(a, v1, w1); accum8(a, v2, w2); accum8(a, v3, w3);
    }
    for (; e < e1; ++e) {
        int s = csr_src[e];
        float w = csr_norm[e];
        uint4 v = H[(size_t)s * (NB * 16) + l];
        accum8(a, v, w);
    }
    const float* bp = bias + c0;
    uint4 o;
    o.x = packbf(fmaxf(a[0] + bp[0], 0.f), fmaxf(a[1] + bp[1], 0.f));
    o.y = packbf(fmaxf(a[2] + bp[2], 0.f), fmaxf(a[3] + bp[3], 0.f));
    o.z = packbf(fmaxf(a[4] + bp[4], 0.f), fmaxf(a[5] + bp[5], 0.f));
    o.w = packbf(fmaxf(a[6] + bp[6], 0.f), fmaxf(a[7] + bp[7], 0.f));
    Z[(size_t)n * (NB * 16) + l] = o;
}

// ---------------- MFMA GEMM: H2 = Z1 @ W2  (out bf16 row-major) ----------------

__global__ __launch_bounds__(256) void k_gemm_h2(const unsigned short* __restrict__ A,
                                                 const unsigned short* __restrict__ W,
                                                 unsigned short* __restrict__ Out, int rows) {
    int tid = threadIdx.x, w = tid >> 6, l = tid & 63, lr = l & 15, lk = l >> 4;
    int rblk = blockIdx.x * 64;
    int rowA = rblk + w * 16 + lr;
    bool okA = rowA < rows;
    const bf8* Ap = (const bf8*)(A + (size_t)rowA * HIDDEN);
    const bf8* Bp = (const bf8*)W;
    fx4 acc[8];
#pragma unroll
    for (int n = 0; n < 8; ++n) acc[n] = (fx4){0.f, 0.f, 0.f, 0.f};
#pragma unroll
    for (int ks = 0; ks < 4; ++ks) {
        bf8 a = okA ? Ap[4 * ks + lk] : (bf8){0, 0, 0, 0, 0, 0, 0, 0};
#pragma unroll
        for (int n = 0; n < 8; ++n) {
            bf8 b = Bp[(size_t)(16 * n + lr) * 16 + 4 * ks + lk];
            acc[n] = __builtin_amdgcn_mfma_f32_16x16x32_bf16(a, b, acc[n], 0, 0, 0);
        }
    }
#pragma unroll
    for (int n = 0; n < 8; ++n)
#pragma unroll
        for (int r = 0; r < 4; ++r) {
            int row = rblk + w * 16 + lk * 4 + r;
            if (row < rows) Out[(size_t)row * HIDDEN + 16 * n + lr] = f2bf(acc[n][r]);
        }
}

// ---------------- mega GRU: all 7 timesteps in one launch, h in registers + LDS exchange ----------------
// Block owns GRUROWS=80 rows (5 tiles x 16). Wave w owns hidden cols [w*16, w*16+16).
// Per lane: hold h (f32) for rows {16m + lk*4 + r} x col c -> hreg[5][4].
// A-operand h (bf16) exchanged via double-buffered XOR-swizzled LDS (one barrier per t).
// Z2all[t] read from global; Hf written once at the end.

__global__ __launch_bounds__(512, 1) void k_megagru(const unsigned short* __restrict__ Z2all,
                                                    float* __restrict__ Hf,
                                                    const unsigned short* __restrict__ Wih,
                                                    const unsigned short* __restrict__ Whh,
                                                    const float* __restrict__ bfold,
                                                    const float* __restrict__ bhh, int rows) {
    __shared__ __align__(16) char hlds[2 * GRUROWS * HIDDEN * 2];  // 40 KB
    const int HALF = GRUROWS * HIDDEN * 2;                          // 20480 B
    int tid = threadIdx.x, w = tid >> 6, l = tid & 63, lr = l & 15, lk = l >> 4;
    int row0 = blockIdx.x * GRUROWS;
    int c = w * 16 + lr;

    // persistent B fragments: 3 gates x {W_ih, W_hh}
    bf8 Bi[3][4], Bh[3][4];
    const bf8* BiP = (const bf8*)Wih;
    const bf8* BhP = (const bf8*)Whh;
#pragma unroll
    for (int g = 0; g < 3; ++g)
#pragma unroll
        for (int ks = 0; ks < 4; ++ks) {
            int rw = g * HIDDEN + c;
            Bi[g][ks] = BiP[(size_t)rw * 16 + 4 * ks + lk];
            Bh[g][ks] = BhP[(size_t)rw * 16 + 4 * ks + lk];
        }

    float bf_r = bfold[c], bf_z = bfold[HIDDEN + c], bf_n = bfold[2 * HIDDEN + c];
    float bh_n = bhh[2 * HIDDEN + c];

    // zero h buffer 0 (h_0 = 0)
    for (int i = tid; i < GRUROWS * HIDDEN / 2; i += 512) ((unsigned int*)hlds)[i] = 0u;
    __syncthreads();

    float hreg[5][4];
#pragma unroll
    for (int m = 0; m < 5; ++m)
#pragma unroll
        for (int r = 0; r < 4; ++r) hreg[m][r] = 0.f;

    int p = 0;
    for (int t = 0; t < LOOKBACK; ++t) {
        const unsigned short* z2t = Z2all + ((size_t)t * rows + row0) * HIDDEN;
#pragma unroll
        for (int m = 0; m < 5; ++m) {
            // A (z2) from global
            bf8 az[4];
            const bf8* zp = (const bf8*)(z2t + (size_t)(16 * m + lr) * HIDDEN);
#pragma unroll
            for (int ks = 0; ks < 4; ++ks) az[ks] = zp[4 * ks + lk];
            // A (h) from LDS, XOR-swizzled
            bf8 ah[4];
#pragma unroll
            for (int ks = 0; ks < 4; ++ks) {
                int byte = p * HALF + (16 * m + lr) * 256 + ks * 64 + lk * 16;
                byte ^= (lr & 7) << 4;
                ah[ks] = *(const bf8*)(hlds + byte);
            }
            fx4 ai[3], ag[3];
#pragma unroll
            for (int g = 0; g < 3; ++g) { ai[g] = (fx4){0.f, 0.f, 0.f, 0.f}; ag[g] = (fx4){0.f, 0.f, 0.f, 0.f}; }
#pragma unroll
            for (int ks = 0; ks < 4; ++ks)
#pragma unroll
                for (int g = 0; g < 3; ++g) {
                    ai[g] = __builtin_amdgcn_mfma_f32_16x16x32_bf16(az[ks], Bi[g][ks], ai[g], 0, 0, 0);
                    ag[g] = __builtin_amdgcn_mfma_f32_16x16x32_bf16(ah[ks], Bh[g][ks], ag[g], 0, 0, 0);
                }
            // gate epilogue: hold is in registers; write h_{t+1} bf16 to the other LDS buffer
#pragma unroll
            for (int r = 0; r < 4; ++r) {
                int row = 16 * m + lk * 4 + r;
                float hold = hreg[m][r];
                float rr = sigm(ai[0][r] + bf_r + ag[0][r]);
                float zz = sigm(ai[1][r] + bf_z + ag[1][r]);
                float nn = ftanh(ai[2][r] + bf_n + rr * (ag[2][r] + bh_n));
                float hnew = (1.0f - zz) * nn + zz * hold;
                hreg[m][r] = hnew;
                int byte = (p ^ 1) * HALF + row * 256 + c * 2;
                byte ^= (row & 7) << 4;
                *(unsigned short*)(hlds + byte) = f2bf(hnew);
            }
        }
        __syncthreads();  // h_{t+1} buffer complete before next t reads it
        p ^= 1;
    }

    // final h -> global f32
#pragma unroll
    for (int m = 0; m < 5; ++m)
#pragma unroll
        for (int r = 0; r < 4; ++r)
            Hf[(size_t)(row0 + 16 * m + lk * 4 + r) * HIDDEN + c] = hreg[m][r];
}

// ---------------- output head: softmax(h @ W_out + b_out) ----------------

template<int NB>
__global__ __launch_bounds__(256) void k_out(const float* __restrict__ Hc, const float* __restrict__ Wo,
                                             const float* __restrict__ bo, float* __restrict__ out,
                                             int dayBase) {
    int rr = blockIdx.x * 4 + (threadIdx.x >> 6);
    if (rr >= N_NODES * NB) return;
    int lane = threadIdx.x & 63;
    float2 hv = ((const float2*)(Hc + (size_t)rr * HIDDEN))[lane];
    float l[5];
#pragma unroll
    for (int j = 0; j < 5; ++j) {
        float p = hv.x * Wo[(2 * lane) * 5 + j] + hv.y * Wo[(2 * lane + 1) * 5 + j];
#pragma unroll
        for (int s = 1; s < 64; s <<= 1) p += __shfl_xor(p, s);
        l[j] = p + bo[j];
    }
    float m = fmaxf(fmaxf(fmaxf(l[0], l[1]), fmaxf(l[2], l[3])), l[4]);
    float e0 = expf(l[0] - m), e1 = expf(l[1] - m), e2 = expf(l[2] - m), e3 = expf(l[3] - m), e4 = expf(l[4] - m);
    float inv = 1.0f / (e0 + e1 + e2 + e3 + e4);
    if (lane < 5) {
        float ej = lane == 0 ? e0 : lane == 1 ? e1 : lane == 2 ? e2 : lane == 3 ? e3 : e4;
        int n = rr / NB, dd = dayBase + rr % NB;
        out[((size_t)dd * N_NODES + n) * 5 + lane] = ej * inv;
    }
}

// ---------------- per-tier pipeline ----------------

template<int NB>
static void run_days(const float* x, const float* W1, const float* b1,
                     const unsigned short* W2T_bf, const float* b2,
                     const unsigned short* Wih_bf, const unsigned short* Whh_bf,
                     const float* b_fold, const float* b_hh,
                     const float* W_out, const float* b_out, float* out,
                     const int* row_start, const int* csr_src, const float* csr_norm,
                     const float* self_norm,
                     float* xa, unsigned short* Z1, unsigned short* H2,
                     unsigned short* Z2all, float* Hf, hipStream_t stream) {
    const int rows = N_NODES * NB;
    const unsigned ngrid = (N_NODES + 3) / 4;
    const unsigned nblk = (unsigned)((rows + 63) / 64);
    const unsigned gru_grid = (unsigned)(rows / GRUROWS);
    const int rounds = NDAYS / NB;
    for (int dd = 0; dd < rounds; ++dd) {
        int dayBase = dd * NB;
        k_aggx<NB><<<ngrid, 256, 0, stream>>>(x, xa, row_start, csr_src, csr_norm, self_norm, dayBase);
        for (int t = 0; t < LOOKBACK; ++t) {
            k_z1<<<(rows + 3) / 4, 256, 0, stream>>>(xa, W1, b1, (unsigned int*)Z1, rows, t);
            k_gemm_h2<<<nblk, 256, 0, stream>>>(Z1, W2T_bf, H2, rows);
            k_agg<NB><<<ngrid, 256, 0, stream>>>((const uint4*)H2,
                                                 (uint4*)(Z2all + (size_t)t * rows * HIDDEN), b2,
                                                 row_start, csr_src, csr_norm, self_norm);
        }
        k_megagru<<<gru_grid, 512, 0, stream>>>(Z2all, Hf, Wih_bf, Whh_bf, b_fold, b_hh, rows);
        k_out<NB><<<(rows + 3) / 4, 256, 0, stream>>>(Hf, W_out, b_out, out, dayBase);
    }
}

// ---------------- launch ----------------

extern "C" void kernel_launch(void* const* d_in, const int* in_sizes, int n_in,
                              void* d_out, int out_size, void* d_ws, size_t ws_size,
                              hipStream_t stream) {
    const float* x     = (const float*)d_in[0];
    const int*   ei    = (const int*)d_in[1];
    const float* W1    = (const float*)d_in[2];
    const float* b1    = (const float*)d_in[3];
    const float* W2    = (const float*)d_in[4];
    const float* b2    = (const float*)d_in[5];
    const float* W_ih  = (const float*)d_in[6];
    const float* W_hh  = (const float*)d_in[7];
    const float* b_ih  = (const float*)d_in[8];
    const float* b_hh  = (const float*)d_in[9];
    const float* W_out = (const float*)d_in[10];
    const float* b_out = (const float*)d_in[11];
    float* out = (float*)d_out;

    size_t off = 0;
    char* wsb = (char*)d_ws;
    auto alloc = [&](size_t bytes) -> void* {
        void* p = wsb + off;
        off = (off + bytes + 255) & ~(size_t)255;
        return p;
    };
    int*            deg       = (int*)alloc(N_NODES * 4);
    int*            cursor    = (int*)alloc(N_NODES * 4);
    int*            row_start = (int*)alloc((N_NODES + 1) * 4);
    float*          dinv      = (float*)alloc(N_NODES * 4);
    float*          self_norm = (float*)alloc(N_NODES * 4);
    unsigned short* W2T_bf    = (unsigned short*)alloc(HIDDEN * HIDDEN * 2);
    unsigned short* Wih_bf    = (unsigned short*)alloc(3 * HIDDEN * HIDDEN * 2);
    unsigned short* Whh_bf    = (unsigned short*)alloc(3 * HIDDEN * HIDDEN * 2);
    float*          b_fold    = (float*)alloc(3 * HIDDEN * 4);
    int*            csr_src   = (int*)alloc(N_EDGES * 4);
    float*          csr_norm  = (float*)alloc(N_EDGES * 4);

    // per-row bytes: xa 140 + Z1 256 + H2 256 + Z2all 7*256 + Hf 512 = 2956
    size_t prep_off = off;
    auto need = [&](int nb) -> size_t {
        return prep_off + (size_t)N_NODES * nb * 2956 + 16384;
    };
    int NBsel = (need(4) <= ws_size) ? 4 : (need(2) <= ws_size) ? 2 : 1;
    int rows = N_NODES * NBsel;

    float*          xa    = (float*)alloc((size_t)rows * XROW * 4);
    unsigned short* Z1    = (unsigned short*)alloc((size_t)rows * HIDDEN * 2);
    unsigned short* H2    = (unsigned short*)alloc((size_t)rows * HIDDEN * 2);
    unsigned short* Z2all = (unsigned short*)alloc((size_t)LOOKBACK * rows * HIDDEN * 2);
    float*          Hf    = (float*)alloc((size_t)rows * HIDDEN * 4);

    // graph + weight prep
    hipMemsetAsync(deg, 0, N_NODES * 4, stream);
    hipMemsetAsync(cursor, 0, N_NODES * 4, stream);
    k_deg<<<(N_EDGES + 255) / 256, 256, 0, stream>>>(ei, deg);
    k_scan<<<1, 1024, 0, stream>>>(deg, row_start);
    k_dinv<<<(N_NODES + 255) / 256, 256, 0, stream>>>(deg, dinv, self_norm);
    k_fill<<<(N_EDGES + 255) / 256, 256, 0, stream>>>(ei, row_start, cursor, dinv, csr_src, csr_norm);
    k_w2t<<<(HIDDEN * HIDDEN + 255) / 256, 256, 0, stream>>>(W2, W2T_bf);
    k_cast<<<(3 * HIDDEN * HIDDEN + 255) / 256, 256, 0, stream>>>(W_ih, Wih_bf, 3 * HIDDEN * HIDDEN);
    k_cast<<<(3 * HIDDEN * HIDDEN + 255) / 256, 256, 0, stream>>>(W_hh, Whh_bf, 3 * HIDDEN * HIDDEN);
    k_bfold<<<2, 256, 0, stream>>>(b_ih, b_hh, b_fold);

    if (NBsel == 4)
        run_days<4>(x, W1, b1, W2T_bf, b2, Wih_bf, Whh_bf, b_fold, b_hh, W_out, b_out, out,
                    row_start, csr_src, csr_norm, self_norm, xa, Z1, H2, Z2all, Hf, stream);
    else if (NBsel == 2)
        run_days<2>(x, W1, b1, W2T_bf, b2, Wih_bf, Whh_bf, b_fold, b_hh, W_out, b_out, out,
                    row_start, csr_src, csr_norm, self_norm, xa, Z1, H2, Z2all, Hf, stream);
    else
        run_days<1>(x, W1, b1, W2T_bf, b2, Wih_bf, Whh_bf, b_fold, b_hh, W_out, b_out, out,
                    row_start, csr_src, csr_norm, self_norm, xa, Z1, H2, Z2all, Hf, stream);
}